// Round 13
// baseline (140.609 us; speedup 1.0000x reference)
//
#include <hip/hip_runtime.h>

typedef unsigned short u16;
typedef unsigned int u32;
typedef __attribute__((ext_vector_type(8))) short bf16x8;
typedef __attribute__((ext_vector_type(4))) float f32x4;
typedef __attribute__((ext_vector_type(16))) float f32x16;
typedef __attribute__((ext_vector_type(4))) u32 u32x4;

#define MFMA16(a, b, c) __builtin_amdgcn_mfma_f32_16x16x32_bf16((a), (b), (c), 0, 0, 0)
#define MFMA32(a, b, c) __builtin_amdgcn_mfma_f32_32x32x16_bf16((a), (b), (c), 0, 0, 0)

__device__ __forceinline__ void async_lds16(void* lds, const void* g) {
  __builtin_amdgcn_global_load_lds(
      (const __attribute__((address_space(1))) void*)g,
      (__attribute__((address_space(3))) void*)lds, 16, 0, 0);
}

__device__ __forceinline__ u16 f2bf(float f) {
  union { float f; unsigned u; } v; v.f = f;
  unsigned r = v.u + 0x7fffu + ((v.u >> 16) & 1u);
  return (u16)(r >> 16);
}

__device__ __forceinline__ u32 cvt_pk_bf16(float lo, float hi) {
  u32 r;
  asm("v_cvt_pk_bf16_f32 %0, %1, %2" : "=v"(r) : "v"(lo), "v"(hi));
  return r;
}

__device__ __forceinline__ float exp2_fast(float x) {
  float r;
  asm("v_exp_f32 %0, %1" : "=v"(r) : "v"(x));
  return r;
}

// swaps a's hi-32 lanes with b's lo-32 lanes
__device__ __forceinline__ void pswap(u32& a, u32& b) {
  asm("v_permlane32_swap_b32 %0, %1" : "+v"(a), "+v"(b));
}

// ---------------- preprocess kernels ----------------

__global__ __launch_bounds__(256) void k_cvt(const float* __restrict__ in, u16* __restrict__ out, int n) {
  int i = (blockIdx.x * 256 + threadIdx.x) * 4;
  if (i >= n) return;
  float4 v = *(const float4*)(in + i);
  ushort4 o;
  o.x = f2bf(v.x); o.y = f2bf(v.y); o.z = f2bf(v.z); o.w = f2bf(v.w);
  *(ushort4*)(out + i) = o;
}

// in: f32 [R][C]  ->  out: bf16 [C][R]
__global__ __launch_bounds__(256) void k_transpose_cvt(const float* __restrict__ in, u16* __restrict__ out,
                                                       int R, int C) {
  __shared__ float tile[32][33];
  int c0 = blockIdx.x * 32, r0 = blockIdx.y * 32;
  int tx = threadIdx.x & 31, ty = threadIdx.x >> 5;
#pragma unroll
  for (int i = 0; i < 32; i += 8)
    tile[ty + i][tx] = in[(long)(r0 + ty + i) * C + c0 + tx];
  __syncthreads();
#pragma unroll
  for (int i = 0; i < 32; i += 8)
    out[(long)(c0 + ty + i) * R + r0 + tx] = f2bf(tile[tx][ty + i]);
}

// V [32 bh][2048 s][64 d] -> Vt [32 bh][64 d][2048 s]   (bf16)
__global__ __launch_bounds__(256) void k_transpose_v(const u16* __restrict__ V, u16* __restrict__ Vt) {
  int bh = blockIdx.z;
  int s0 = blockIdx.x * 32, d0 = blockIdx.y * 32;
  __shared__ u16 tile[32][33];
  int tx = threadIdx.x & 31, ty = threadIdx.x >> 5;
  const u16* Vb = V + (long)bh * 2048 * 64;
  u16* Vtb = Vt + (long)bh * 64 * 2048;
#pragma unroll
  for (int i = 0; i < 32; i += 8)
    tile[ty + i][tx] = Vb[(long)(s0 + ty + i) * 64 + d0 + tx];
  __syncthreads();
#pragma unroll
  for (int i = 0; i < 32; i += 8)
    Vtb[(long)(d0 + ty + i) * 2048 + s0 + tx] = tile[tx][ty + i];
}

// ---------------- NT GEMM core: C[128x128] = A[128xK] * Bt[128xK]^T ----------------
// Double-buffered LDS, stage-before-compute, ONE barrier per K-step (T3-minimum):
// prologue stage(0); loop: barrier (drains loads issued a full iteration ago) ->
// issue stage(kt+1) into alt buffer -> compute tile kt from current buffer.

__device__ __forceinline__ void gemm_core(const u16* __restrict__ A, const u16* __restrict__ Bt,
                                          int K, long row0, long col0,
                                          u16* sA, u16* sB, f32x4 acc[4][4]) {
  const int t = threadIdx.x;
  const int lane = t & 63, g = lane >> 4, m16 = lane & 15;
  const int wid = t >> 6, wr = wid >> 1, wc = wid & 1;
  const int ldsbase = (t & ~63) << 4;
  const int nkt = K >> 6;

  auto stage = [&](int buf, int kt) {
    const int k0 = kt << 6;
#pragma unroll
    for (int it = 0; it < 4; ++it) {
      int i = it * 256 + t;
      int r = i >> 3, c = i & 7;
      int cs = c ^ (r & 7);
      async_lds16((char*)sA + buf * 16384 + it * 4096 + ldsbase, A + (row0 + r) * K + k0 + cs * 8);
    }
#pragma unroll
    for (int it = 0; it < 4; ++it) {
      int i = it * 256 + t;
      int r = i >> 3, c = i & 7;
      int cs = c ^ (r & 7);
      async_lds16((char*)sB + buf * 16384 + it * 4096 + ldsbase, Bt + (col0 + r) * K + k0 + cs * 8);
    }
  };

  stage(0, 0);
  int cur = 0;
  for (int kt = 0; kt < nkt; ++kt) {
    __syncthreads();  // drains prior stage (issued one full iteration ago) + frees alt buffer
    if (kt + 1 < nkt) stage(cur ^ 1, kt + 1);
    const char* bA = (const char*)sA + cur * 16384;
    const char* bB = (const char*)sB + cur * 16384;
#pragma unroll
    for (int kk6 = 0; kk6 < 2; ++kk6) {
      const int ke = kk6 * 32 + 8 * g;
      bf16x8 av[4], bv[4];
#pragma unroll
      for (int mi = 0; mi < 4; ++mi) {
        int row = wr * 64 + mi * 16 + m16;
        av[mi] = *(const bf16x8*)(bA + (row << 7) + ((ke << 1) ^ ((row & 7) << 4)));
      }
#pragma unroll
      for (int ni = 0; ni < 4; ++ni) {
        int row = wc * 64 + ni * 16 + m16;
        bv[ni] = *(const bf16x8*)(bB + (row << 7) + ((ke << 1) ^ ((row & 7) << 4)));
      }
#pragma unroll
      for (int mi = 0; mi < 4; ++mi)
#pragma unroll
        for (int ni = 0; ni < 4; ++ni)
          acc[mi][ni] = MFMA16(av[mi], bv[ni], acc[mi][ni]);
    }
    cur ^= 1;
  }
}

// GEMM1: xb[4096][1024] x wqkvT[3072][1024]^T -> scatter Q,K,V [B,H,S,D] bf16
// XCD row-panel swizzle: xcd = L&7 owns row-tiles [xcd*4, xcd*4+4).
__global__ __launch_bounds__(256) void k_gemm_qkv(const u16* __restrict__ xb, const u16* __restrict__ wT,
                                                  u16* __restrict__ Qo, u16* __restrict__ Ko,
                                                  u16* __restrict__ Vo) {
  __shared__ __align__(16) u16 sA[2 * 128 * 64];
  __shared__ __align__(16) u16 sB[2 * 128 * 64];
  f32x4 acc[4][4];
  const f32x4 z = {0.f, 0.f, 0.f, 0.f};
#pragma unroll
  for (int mi = 0; mi < 4; ++mi)
#pragma unroll
    for (int ni = 0; ni < 4; ++ni) acc[mi][ni] = z;
  const int L = blockIdx.x;
  const int xcd = L & 7, idx = L >> 3;          // idx 0..95
  const int rowt = xcd * 4 + (idx & 3);         // 0..31
  const int colt = idx >> 2;                    // 0..23
  long row0 = (long)rowt * 128, col0 = (long)colt * 128;
  gemm_core(xb, wT, 1024, row0, col0, sA, sB, acc);
  const int t = threadIdx.x;
  const int lane = t & 63, g = lane >> 4, m16 = lane & 15;
  const int wid = t >> 6, wr = wid >> 1, wc = wid & 1;
#pragma unroll
  for (int mi = 0; mi < 4; ++mi) {
#pragma unroll
    for (int ni = 0; ni < 4; ++ni) {
      int col = (int)col0 + wc * 64 + ni * 16 + m16;
      int h = col / 192, rem = col - h * 192;
      int which = rem >> 6, d = rem & 63;
#pragma unroll
      for (int r = 0; r < 4; ++r) {
        int row = (int)row0 + wr * 64 + mi * 16 + 4 * g + r;
        int b = row >> 11, s = row & 2047;
        long off = (((long)(b * 16 + h)) * 2048 + s) * 64 + d;
        float v = acc[mi][ni][r];
        if (which == 0) Qo[off] = f2bf(v * 0.18033688f);  // 0.125 * log2(e)
        else if (which == 1) Ko[off] = f2bf(v);
        else Vo[off] = f2bf(v);
      }
    }
  }
}

// GEMM2: Ob[4096][1024] x woutT[1024][1024]^T -> out f32 [4096][1024]
__global__ __launch_bounds__(256) void k_gemm_out(const u16* __restrict__ Ob, const u16* __restrict__ wT,
                                                  float* __restrict__ out) {
  __shared__ __align__(16) u16 sA[2 * 128 * 64];
  __shared__ __align__(16) u16 sB[2 * 128 * 64];
  f32x4 acc[4][4];
  const f32x4 z = {0.f, 0.f, 0.f, 0.f};
#pragma unroll
  for (int mi = 0; mi < 4; ++mi)
#pragma unroll
    for (int ni = 0; ni < 4; ++ni) acc[mi][ni] = z;
  const int L = blockIdx.x;
  const int xcd = L & 7, idx = L >> 3;          // idx 0..31
  const int rowt = xcd * 4 + (idx & 3);         // 0..31
  const int colt = idx >> 2;                    // 0..7
  long row0 = (long)rowt * 128, col0 = (long)colt * 128;
  gemm_core(Ob, wT, 1024, row0, col0, sA, sB, acc);
  const int t = threadIdx.x;
  const int lane = t & 63, g = lane >> 4, m16 = lane & 15;
  const int wid = t >> 6, wr = wid >> 1, wc = wid & 1;
#pragma unroll
  for (int mi = 0; mi < 4; ++mi) {
#pragma unroll
    for (int ni = 0; ni < 4; ++ni) {
#pragma unroll
      for (int r = 0; r < 4; ++r) {
        long row = row0 + wr * 64 + mi * 16 + 4 * g + r;
        long col = col0 + wc * 64 + ni * 16 + m16;
        out[row * 1024 + col] = acc[mi][ni][r];
      }
    }
  }
}

// ---------------- causal flash attention: LDS-shared K/V + lean in-register body ----------------
// Block = 256 thr = 4 waves, QBLK=128 (wave w -> strip qt*4+w), KVBLK=64, K/V
// double-buffered in LDS (32KB) via global_load_lds shared by all 4 waves. Per-wave
// math: swapped QK 32x32 (lane owns q-col), fixed-max exp2 softmax, permlane P->PV.
// One barrier per tile; wave-dead sub-blocks skipped.

template <bool DIAG>
__device__ __forceinline__ void attn_sub(const char* Kt, const char* Vt, int bsub,
                                         bf16x8 qf0, bf16x8 qf1, bf16x8 qf2, bf16x8 qf3,
                                         f32x16& acc0, f32x16& acc1, float& l,
                                         int q5, int hi) {
  const int x7 = q5 & 7;
  const int rowK = (bsub * 32 + q5) << 7;
  bf16x8 k0 = *(const bf16x8*)(Kt + rowK + (((0 + hi) ^ x7) << 4));
  bf16x8 k1 = *(const bf16x8*)(Kt + rowK + (((2 + hi) ^ x7) << 4));
  bf16x8 k2 = *(const bf16x8*)(Kt + rowK + (((4 + hi) ^ x7) << 4));
  bf16x8 k3 = *(const bf16x8*)(Kt + rowK + (((6 + hi) ^ x7) << 4));
  const int rowV0 = q5 << 7, rowV1 = (q5 + 32) << 7;
  bf16x8 v00 = *(const bf16x8*)(Vt + rowV0 + (((bsub * 4 + 0 + hi) ^ x7) << 4));
  bf16x8 v01 = *(const bf16x8*)(Vt + rowV1 + (((bsub * 4 + 0 + hi) ^ x7) << 4));
  bf16x8 v10 = *(const bf16x8*)(Vt + rowV0 + (((bsub * 4 + 2 + hi) ^ x7) << 4));
  bf16x8 v11 = *(const bf16x8*)(Vt + rowV1 + (((bsub * 4 + 2 + hi) ^ x7) << 4));

  f32x16 s;
#pragma unroll
  for (int r = 0; r < 16; ++r) s[r] = 0.f;
  s = MFMA32(k0, qf0, s);
  s = MFMA32(k1, qf1, s);
  s = MFMA32(k2, qf2, s);
  s = MFMA32(k3, qf3, s);

  float p[16];
#pragma unroll
  for (int r = 0; r < 16; ++r) {
    float pv = exp2_fast(s[r]);
    if (DIAG) {
      int crow = (r & 3) + 8 * (r >> 2) + 4 * hi;
      pv = (crow <= q5) ? pv : 0.f;
    }
    p[r] = pv;
  }
  l += (((p[0] + p[1]) + (p[2] + p[3])) + ((p[4] + p[5]) + (p[6] + p[7]))) +
       (((p[8] + p[9]) + (p[10] + p[11])) + ((p[12] + p[13]) + (p[14] + p[15])));

  u32 a0 = cvt_pk_bf16(p[0], p[1]), a1 = cvt_pk_bf16(p[2], p[3]);
  u32 b0 = cvt_pk_bf16(p[4], p[5]), b1 = cvt_pk_bf16(p[6], p[7]);
  pswap(a0, b0); pswap(a1, b1);
  u32 c0 = cvt_pk_bf16(p[8], p[9]), c1 = cvt_pk_bf16(p[10], p[11]);
  u32 d0 = cvt_pk_bf16(p[12], p[13]), d1 = cvt_pk_bf16(p[14], p[15]);
  pswap(c0, d0); pswap(c1, d1);
  u32x4 t0; t0[0] = a0; t0[1] = a1; t0[2] = b0; t0[3] = b1;
  u32x4 t1; t1[0] = c0; t1[1] = c1; t1[2] = d0; t1[3] = d1;
  bf16x8 pa0 = __builtin_bit_cast(bf16x8, t0);  // keys +0..15, k-slot order
  bf16x8 pa1 = __builtin_bit_cast(bf16x8, t1);  // keys +16..31

  acc0 = MFMA32(pa0, v00, acc0);
  acc1 = MFMA32(pa0, v01, acc1);
  acc0 = MFMA32(pa1, v10, acc0);
  acc1 = MFMA32(pa1, v11, acc1);
}

// Q,K: [32 bh][2048][64] bf16 (Q pre-scaled by 0.125*log2e); Vt: [32 bh][64][2048] bf16
__global__ __launch_bounds__(256) void k_attn(const u16* __restrict__ Qg, const u16* __restrict__ Kg,
                                              const u16* __restrict__ Vtg, u16* __restrict__ Og) {
  __shared__ __align__(16) u16 sK[2][64 * 64];  // [key][d] swizzled, 8KB per buffer
  __shared__ __align__(16) u16 sV[2][64 * 64];  // [d][key] swizzled
  const int t = threadIdx.x;
  const int lane = t & 63, q5 = lane & 31, hi = lane >> 5, w = t >> 6;
  const int L = blockIdx.x;
  const int bh = L & 31, q16 = L >> 5;                 // XCD affinity: L%8 == bh%8
  const int qt = (q16 < 8) ? q16 : (23 - q16);         // (qt, 15-qt) complementary ordering
  const int b = bh >> 4, h = bh & 15;
  const u16* Qh = Qg + (long)bh * 131072;
  const u16* Kh = Kg + (long)bh * 131072;
  const u16* Vh = Vtg + (long)bh * 131072;
  char* sKb = (char*)sK;
  char* sVb = (char*)sV;

  const int strip = qt * 4 + w;
  const int q0w = strip * 32;
  const int nkt = 2 * qt + 2;  // tiles staged by this block

  // Q fragments for this wave's strip
  const u16* Qp = Qh + (long)(q0w + q5) * 64 + hi * 8;
  bf16x8 qf0 = *(const bf16x8*)(Qp);
  bf16x8 qf1 = *(const bf16x8*)(Qp + 16);
  bf16x8 qf2 = *(const bf16x8*)(Qp + 32);
  bf16x8 qf3 = *(const bf16x8*)(Qp + 48);

  f32x16 acc0, acc1;
#pragma unroll
  for (int r = 0; r < 16; ++r) { acc0[r] = 0.f; acc1[r] = 0.f; }
  float l = 0.f;

  auto stage = [&](int buf, int kt) {
    const int kbase = kt << 6;
#pragma unroll
    for (int ps = 0; ps < 2; ++ps) {
      int i = ps * 256 + t;
      int r = i >> 3, c = i & 7, cs = c ^ (r & 7);
      async_lds16(sKb + buf * 8192 + i * 16, Kh + (long)(kbase + r) * 64 + cs * 8);
    }
#pragma unroll
    for (int ps = 0; ps < 2; ++ps) {
      int i = ps * 256 + t;
      int d = i >> 3, c = i & 7, cs = c ^ (d & 7);
      async_lds16(sVb + buf * 8192 + i * 16, Vh + (long)d * 2048 + kbase + cs * 8);
    }
  };

  stage(0, 0);
  int cur = 0;
  for (int kt = 0; kt < nkt; ++kt) {
    __syncthreads();  // tile kt staged (vmcnt drain) + everyone done reading buf cur^1
    if (kt + 1 < nkt) stage(cur ^ 1, kt + 1);
    const char* Kt = sKb + cur * 8192;
    const char* Vt = sVb + cur * 8192;
    const int c2 = 2 * kt;
    if (c2 <= strip) {
      if (c2 == strip) attn_sub<true>(Kt, Vt, 0, qf0, qf1, qf2, qf3, acc0, acc1, l, q5, hi);
      else             attn_sub<false>(Kt, Vt, 0, qf0, qf1, qf2, qf3, acc0, acc1, l, q5, hi);
    }
    if (c2 + 1 <= strip) {
      if (c2 + 1 == strip) attn_sub<true>(Kt, Vt, 1, qf0, qf1, qf2, qf3, acc0, acc1, l, q5, hi);
      else                 attn_sub<false>(Kt, Vt, 1, qf0, qf1, qf2, qf3, acc0, acc1, l, q5, hi);
    }
    cur ^= 1;
  }

  // epilogue (no LDS use -> no final barrier)
  l += __shfl_xor(l, 32);
  float linv = 1.0f / l;
  const long orow_base = (long)b * 2048;
#pragma unroll
  for (int r = 0; r < 16; ++r) {
    int crow = (r & 3) + 8 * (r >> 2) + 4 * hi;
    float lf = __shfl(linv, crow);
    long orow = orow_base + q0w + crow;
    Og[orow * 1024 + h * 64 + q5] = f2bf(acc0[r] * lf);
    Og[orow * 1024 + h * 64 + 32 + q5] = f2bf(acc1[r] * lf);
  }
}

// ---------------- launch ----------------

extern "C" void kernel_launch(void* const* d_in, const int* in_sizes, int n_in,
                              void* d_out, int out_size, void* d_ws, size_t ws_size,
                              hipStream_t stream) {
  const float* x = (const float*)d_in[0];
  const float* w_qkv = (const float*)d_in[1];
  const float* w_out = (const float*)d_in[2];
  float* out = (float*)d_out;
  char* ws = (char*)d_ws;

  u16* xb    = (u16*)(ws + 0);          // 8 MB, reused as Ob after attention
  u16* wqkvT = (u16*)(ws + 8388608L);   // 6 MB
  u16* woutT = (u16*)(ws + 14680064L);  // 2 MB
  u16* Qb    = (u16*)(ws + 16777216L);  // 8 MB
  u16* Kb    = (u16*)(ws + 25165824L);  // 8 MB
  u16* Vb    = (u16*)(ws + 33554432L);  // 8 MB
  u16* Vt    = (u16*)(ws + 41943040L);  // 8 MB  (total 48 MB)
  u16* Ob    = xb;                      // alias: xb dead after GEMM1

  k_cvt<<<4096, 256, 0, stream>>>(x, xb, 4194304);
  k_transpose_cvt<<<dim3(96, 32), 256, 0, stream>>>(w_qkv, wqkvT, 1024, 3072);
  k_transpose_cvt<<<dim3(32, 32), 256, 0, stream>>>(w_out, woutT, 1024, 1024);
  k_gemm_qkv<<<dim3(768), 256, 0, stream>>>(xb, wqkvT, Qb, Kb, Vb);
  k_transpose_v<<<dim3(64, 2, 32), 256, 0, stream>>>(Vb, Vt);
  k_attn<<<dim3(512), 256, 0, stream>>>(Qb, Kb, Vt, Ob);
  k_gemm_out<<<dim3(256), 256, 0, stream>>>(Ob, woutT, out);
}

// Round 14
// 124.676 us; speedup vs baseline: 1.1278x; 1.1278x over previous
//
#include <hip/hip_runtime.h>

typedef unsigned short u16;
typedef unsigned int u32;
typedef __attribute__((ext_vector_type(8))) short bf16x8;
typedef __attribute__((ext_vector_type(4))) float f32x4;
typedef __attribute__((ext_vector_type(16))) float f32x16;
typedef __attribute__((ext_vector_type(4))) u32 u32x4;

#define MFMA16(a, b, c) __builtin_amdgcn_mfma_f32_16x16x32_bf16((a), (b), (c), 0, 0, 0)
#define MFMA32(a, b, c) __builtin_amdgcn_mfma_f32_32x32x16_bf16((a), (b), (c), 0, 0, 0)

__device__ __forceinline__ void async_lds16(void* lds, const void* g) {
  __builtin_amdgcn_global_load_lds(
      (const __attribute__((address_space(1))) void*)g,
      (__attribute__((address_space(3))) void*)lds, 16, 0, 0);
}

__device__ __forceinline__ u16 f2bf(float f) {
  union { float f; unsigned u; } v; v.f = f;
  unsigned r = v.u + 0x7fffu + ((v.u >> 16) & 1u);
  return (u16)(r >> 16);
}

__device__ __forceinline__ u32 cvt_pk_bf16(float lo, float hi) {
  u32 r;
  asm("v_cvt_pk_bf16_f32 %0, %1, %2" : "=v"(r) : "v"(lo), "v"(hi));
  return r;
}

__device__ __forceinline__ float exp2_fast(float x) {
  float r;
  asm("v_exp_f32 %0, %1" : "=v"(r) : "v"(x));
  return r;
}

// swaps a's hi-32 lanes with b's lo-32 lanes
__device__ __forceinline__ void pswap(u32& a, u32& b) {
  asm("v_permlane32_swap_b32 %0, %1" : "+v"(a), "+v"(b));
}

// ---------------- preprocess kernels ----------------

__global__ __launch_bounds__(256) void k_cvt(const float* __restrict__ in, u16* __restrict__ out, int n) {
  int i = (blockIdx.x * 256 + threadIdx.x) * 4;
  if (i >= n) return;
  float4 v = *(const float4*)(in + i);
  ushort4 o;
  o.x = f2bf(v.x); o.y = f2bf(v.y); o.z = f2bf(v.z); o.w = f2bf(v.w);
  *(ushort4*)(out + i) = o;
}

// in: f32 [R][C]  ->  out: bf16 [C][R]
__global__ __launch_bounds__(256) void k_transpose_cvt(const float* __restrict__ in, u16* __restrict__ out,
                                                       int R, int C) {
  __shared__ float tile[32][33];
  int c0 = blockIdx.x * 32, r0 = blockIdx.y * 32;
  int tx = threadIdx.x & 31, ty = threadIdx.x >> 5;
#pragma unroll
  for (int i = 0; i < 32; i += 8)
    tile[ty + i][tx] = in[(long)(r0 + ty + i) * C + c0 + tx];
  __syncthreads();
#pragma unroll
  for (int i = 0; i < 32; i += 8)
    out[(long)(c0 + ty + i) * R + r0 + tx] = f2bf(tile[tx][ty + i]);
}

// V [32 bh][2048 s][64 d] -> Vt [32 bh][64 d][2048 s]   (bf16)
__global__ __launch_bounds__(256) void k_transpose_v(const u16* __restrict__ V, u16* __restrict__ Vt) {
  int bh = blockIdx.z;
  int s0 = blockIdx.x * 32, d0 = blockIdx.y * 32;
  __shared__ u16 tile[32][33];
  int tx = threadIdx.x & 31, ty = threadIdx.x >> 5;
  const u16* Vb = V + (long)bh * 2048 * 64;
  u16* Vtb = Vt + (long)bh * 64 * 2048;
#pragma unroll
  for (int i = 0; i < 32; i += 8)
    tile[ty + i][tx] = Vb[(long)(s0 + ty + i) * 64 + d0 + tx];
  __syncthreads();
#pragma unroll
  for (int i = 0; i < 32; i += 8)
    Vtb[(long)(d0 + ty + i) * 2048 + s0 + tx] = tile[tx][ty + i];
}

// ---------------- NT GEMM core (counted-vmcnt single-barrier pipeline) ----------------
// BMxBN tile, NW waves (WMxWN), BK=64, double-buffered LDS. 8 async loads per
// thread per K-tile (4 rounds A + 4 rounds B) => vmcnt(8) waits exactly the
// current tile while the next tile's loads stay in flight across the raw
// s_barrier (no compiler vmcnt(0) drain). sched_barrier(0) pins phase edges.

template <int BM, int BN, int NW, int WN, int MR, int NR>
__device__ __forceinline__ void gemm_core_pipe(const u16* __restrict__ A, const u16* __restrict__ Bt,
                                               int K, long row0, long col0,
                                               u16* sA, u16* sB, f32x4 (&acc)[MR][NR]) {
  const int NTHR = NW * 64;
  const int ABYTES = BM * 64 * 2;
  const int BBYTES = BN * 64 * 2;
  const int t = threadIdx.x;
  const int lane = t & 63, g = lane >> 4, m16 = lane & 15;
  const int wid = t >> 6, wr = wid / WN, wc = wid % WN;
  const int nkt = K >> 6;

  auto stage = [&](int buf, int kt) {
    const int k0 = kt << 6;
#pragma unroll
    for (int it = 0; it < ABYTES / (NTHR * 16); ++it) {
      int i = it * NTHR + t;
      int r = i >> 3, c = i & 7, cs = c ^ (r & 7);
      async_lds16((char*)sA + buf * ABYTES + i * 16, A + (row0 + r) * K + k0 + cs * 8);
    }
#pragma unroll
    for (int it = 0; it < BBYTES / (NTHR * 16); ++it) {
      int i = it * NTHR + t;
      int r = i >> 3, c = i & 7, cs = c ^ (r & 7);
      async_lds16((char*)sB + buf * BBYTES + i * 16, Bt + (col0 + r) * K + k0 + cs * 8);
    }
  };

  stage(0, 0);
  stage(1, 1);
  int cur = 0;
  for (int kt = 0; kt < nkt; ++kt) {
    if (kt + 1 < nkt) asm volatile("s_waitcnt vmcnt(8)" ::: "memory");
    else              asm volatile("s_waitcnt vmcnt(0)" ::: "memory");
    __builtin_amdgcn_s_barrier();
    __builtin_amdgcn_sched_barrier(0);
    const char* bA = (const char*)sA + cur * ABYTES;
    const char* bB = (const char*)sB + cur * BBYTES;
#pragma unroll
    for (int kk6 = 0; kk6 < 2; ++kk6) {
      const int ke = kk6 * 32 + 8 * g;
      bf16x8 av[MR], bv[NR];
#pragma unroll
      for (int mi = 0; mi < MR; ++mi) {
        int row = wr * (MR * 16) + mi * 16 + m16;
        av[mi] = *(const bf16x8*)(bA + (row << 7) + ((ke << 1) ^ ((row & 7) << 4)));
      }
#pragma unroll
      for (int ni = 0; ni < NR; ++ni) {
        int row = wc * (NR * 16) + ni * 16 + m16;
        bv[ni] = *(const bf16x8*)(bB + (row << 7) + ((ke << 1) ^ ((row & 7) << 4)));
      }
#pragma unroll
      for (int mi = 0; mi < MR; ++mi)
#pragma unroll
        for (int ni = 0; ni < NR; ++ni)
          acc[mi][ni] = MFMA16(av[mi], bv[ni], acc[mi][ni]);
    }
    __builtin_amdgcn_sched_barrier(0);
    __builtin_amdgcn_s_barrier();
    if (kt + 2 < nkt) stage(cur, kt + 2);
    cur ^= 1;
  }
}

// GEMM1: xb[4096][1024] x wqkvT[3072][1024]^T, 256x256 tile, 512 thr (8 waves 2x4).
// Grid 192 = 1 block/CU. Scatter Q,K,V [B,H,S,D] bf16; Q scaled by 0.125*log2e.
__global__ __launch_bounds__(512, 2) void k_gemm_qkv(const u16* __restrict__ xb, const u16* __restrict__ wT,
                                                     u16* __restrict__ Qo, u16* __restrict__ Ko,
                                                     u16* __restrict__ Vo) {
  __shared__ __align__(16) u16 sA[2 * 256 * 64];  // 64KB
  __shared__ __align__(16) u16 sB[2 * 256 * 64];  // 64KB
  f32x4 acc[8][4];
  const f32x4 z = {0.f, 0.f, 0.f, 0.f};
#pragma unroll
  for (int mi = 0; mi < 8; ++mi)
#pragma unroll
    for (int ni = 0; ni < 4; ++ni) acc[mi][ni] = z;
  const int L = blockIdx.x;
  const int xcd = L & 7, idx = L >> 3;          // idx 0..23
  const int rowt = xcd * 2 + (idx & 1);         // 0..15
  const int colt = idx >> 1;                    // 0..11
  long row0 = (long)rowt * 256, col0 = (long)colt * 256;
  gemm_core_pipe<256, 256, 8, 4, 8, 4>(xb, wT, 1024, row0, col0, sA, sB, acc);
  const int t = threadIdx.x;
  const int lane = t & 63, g = lane >> 4, m16 = lane & 15;
  const int wid = t >> 6, wr = wid >> 2, wc = wid & 3;
#pragma unroll
  for (int mi = 0; mi < 8; ++mi) {
#pragma unroll
    for (int ni = 0; ni < 4; ++ni) {
      int col = (int)col0 + wc * 64 + ni * 16 + m16;
      int h = col / 192, rem = col - h * 192;
      int which = rem >> 6, d = rem & 63;
#pragma unroll
      for (int r = 0; r < 4; ++r) {
        int row = (int)row0 + wr * 128 + mi * 16 + 4 * g + r;
        int b = row >> 11, s = row & 2047;
        long off = (((long)(b * 16 + h)) * 2048 + s) * 64 + d;
        float v = acc[mi][ni][r];
        if (which == 0) Qo[off] = f2bf(v * 0.18033688f);  // 0.125 * log2(e)
        else if (which == 1) Ko[off] = f2bf(v);
        else Vo[off] = f2bf(v);
      }
    }
  }
}

// GEMM2: Ob[4096][1024] x woutT[1024][1024]^T -> out f32 [4096][1024]
// 128x128 tile, 256 thr (4 waves 2x2), same pipelined core. Grid 256 = 1/CU.
__global__ __launch_bounds__(256) void k_gemm_out(const u16* __restrict__ Ob, const u16* __restrict__ wT,
                                                  float* __restrict__ out) {
  __shared__ __align__(16) u16 sA[2 * 128 * 64];  // 32KB
  __shared__ __align__(16) u16 sB[2 * 128 * 64];  // 32KB
  f32x4 acc[4][4];
  const f32x4 z = {0.f, 0.f, 0.f, 0.f};
#pragma unroll
  for (int mi = 0; mi < 4; ++mi)
#pragma unroll
    for (int ni = 0; ni < 4; ++ni) acc[mi][ni] = z;
  const int L = blockIdx.x;
  const int xcd = L & 7, idx = L >> 3;          // idx 0..31
  const int rowt = xcd * 4 + (idx & 3);         // 0..31
  const int colt = idx >> 2;                    // 0..7
  long row0 = (long)rowt * 128, col0 = (long)colt * 128;
  gemm_core_pipe<128, 128, 4, 2, 4, 4>(Ob, wT, 1024, row0, col0, sA, sB, acc);
  const int t = threadIdx.x;
  const int lane = t & 63, g = lane >> 4, m16 = lane & 15;
  const int wid = t >> 6, wr = wid >> 1, wc = wid & 1;
#pragma unroll
  for (int mi = 0; mi < 4; ++mi) {
#pragma unroll
    for (int ni = 0; ni < 4; ++ni) {
#pragma unroll
      for (int r = 0; r < 4; ++r) {
        long row = row0 + wr * 64 + mi * 16 + 4 * g + r;
        long col = col0 + wc * 64 + ni * 16 + m16;
        out[row * 1024 + col] = acc[mi][ni][r];
      }
    }
  }
}

// ---------------- causal flash attention: LDS-shared K/V + lean in-register body ----------------
// Block = 256 thr = 4 waves, QBLK=128 (wave w -> strip qt*4+w), KVBLK=64, K/V
// double-buffered in LDS (32KB) via global_load_lds shared by all 4 waves. Per-wave
// math: swapped QK 32x32 (lane owns q-col), fixed-max exp2 softmax, permlane P->PV.
// One barrier per tile; wave-dead sub-blocks skipped.

template <bool DIAG>
__device__ __forceinline__ void attn_sub(const char* Kt, const char* Vt, int bsub,
                                         bf16x8 qf0, bf16x8 qf1, bf16x8 qf2, bf16x8 qf3,
                                         f32x16& acc0, f32x16& acc1, float& l,
                                         int q5, int hi) {
  const int x7 = q5 & 7;
  const int rowK = (bsub * 32 + q5) << 7;
  bf16x8 k0 = *(const bf16x8*)(Kt + rowK + (((0 + hi) ^ x7) << 4));
  bf16x8 k1 = *(const bf16x8*)(Kt + rowK + (((2 + hi) ^ x7) << 4));
  bf16x8 k2 = *(const bf16x8*)(Kt + rowK + (((4 + hi) ^ x7) << 4));
  bf16x8 k3 = *(const bf16x8*)(Kt + rowK + (((6 + hi) ^ x7) << 4));
  const int rowV0 = q5 << 7, rowV1 = (q5 + 32) << 7;
  bf16x8 v00 = *(const bf16x8*)(Vt + rowV0 + (((bsub * 4 + 0 + hi) ^ x7) << 4));
  bf16x8 v01 = *(const bf16x8*)(Vt + rowV1 + (((bsub * 4 + 0 + hi) ^ x7) << 4));
  bf16x8 v10 = *(const bf16x8*)(Vt + rowV0 + (((bsub * 4 + 2 + hi) ^ x7) << 4));
  bf16x8 v11 = *(const bf16x8*)(Vt + rowV1 + (((bsub * 4 + 2 + hi) ^ x7) << 4));

  f32x16 s;
#pragma unroll
  for (int r = 0; r < 16; ++r) s[r] = 0.f;
  s = MFMA32(k0, qf0, s);
  s = MFMA32(k1, qf1, s);
  s = MFMA32(k2, qf2, s);
  s = MFMA32(k3, qf3, s);

  float p[16];
#pragma unroll
  for (int r = 0; r < 16; ++r) {
    float pv = exp2_fast(s[r]);
    if (DIAG) {
      int crow = (r & 3) + 8 * (r >> 2) + 4 * hi;
      pv = (crow <= q5) ? pv : 0.f;
    }
    p[r] = pv;
  }
  l += (((p[0] + p[1]) + (p[2] + p[3])) + ((p[4] + p[5]) + (p[6] + p[7]))) +
       (((p[8] + p[9]) + (p[10] + p[11])) + ((p[12] + p[13]) + (p[14] + p[15])));

  u32 a0 = cvt_pk_bf16(p[0], p[1]), a1 = cvt_pk_bf16(p[2], p[3]);
  u32 b0 = cvt_pk_bf16(p[4], p[5]), b1 = cvt_pk_bf16(p[6], p[7]);
  pswap(a0, b0); pswap(a1, b1);
  u32 c0 = cvt_pk_bf16(p[8], p[9]), c1 = cvt_pk_bf16(p[10], p[11]);
  u32 d0 = cvt_pk_bf16(p[12], p[13]), d1 = cvt_pk_bf16(p[14], p[15]);
  pswap(c0, d0); pswap(c1, d1);
  u32x4 t0; t0[0] = a0; t0[1] = a1; t0[2] = b0; t0[3] = b1;
  u32x4 t1; t1[0] = c0; t1[1] = c1; t1[2] = d0; t1[3] = d1;
  bf16x8 pa0 = __builtin_bit_cast(bf16x8, t0);  // keys +0..15, k-slot order
  bf16x8 pa1 = __builtin_bit_cast(bf16x8, t1);  // keys +16..31

  acc0 = MFMA32(pa0, v00, acc0);
  acc1 = MFMA32(pa0, v01, acc1);
  acc0 = MFMA32(pa1, v10, acc0);
  acc1 = MFMA32(pa1, v11, acc1);
}

// Q,K: [32 bh][2048][64] bf16 (Q pre-scaled by 0.125*log2e); Vt: [32 bh][64][2048] bf16
__global__ __launch_bounds__(256) void k_attn(const u16* __restrict__ Qg, const u16* __restrict__ Kg,
                                              const u16* __restrict__ Vtg, u16* __restrict__ Og) {
  __shared__ __align__(16) u16 sK[2][64 * 64];  // [key][d] swizzled, 8KB per buffer
  __shared__ __align__(16) u16 sV[2][64 * 64];  // [d][key] swizzled
  const int t = threadIdx.x;
  const int lane = t & 63, q5 = lane & 31, hi = lane >> 5, w = t >> 6;
  const int L = blockIdx.x;
  const int bh = L & 31, q16 = L >> 5;                 // XCD affinity: L%8 == bh%8
  const int qt = (q16 < 8) ? q16 : (23 - q16);         // (qt, 15-qt) complementary ordering
  const int b = bh >> 4, h = bh & 15;
  const u16* Qh = Qg + (long)bh * 131072;
  const u16* Kh = Kg + (long)bh * 131072;
  const u16* Vh = Vtg + (long)bh * 131072;
  char* sKb = (char*)sK;
  char* sVb = (char*)sV;

  const int strip = qt * 4 + w;
  const int q0w = strip * 32;
  const int nkt = 2 * qt + 2;  // tiles staged by this block

  // Q fragments for this wave's strip
  const u16* Qp = Qh + (long)(q0w + q5) * 64 + hi * 8;
  bf16x8 qf0 = *(const bf16x8*)(Qp);
  bf16x8 qf1 = *(const bf16x8*)(Qp + 16);
  bf16x8 qf2 = *(const bf16x8*)(Qp + 32);
  bf16x8 qf3 = *(const bf16x8*)(Qp + 48);

  f32x16 acc0, acc1;
#pragma unroll
  for (int r = 0; r < 16; ++r) { acc0[r] = 0.f; acc1[r] = 0.f; }
  float l = 0.f;

  auto stage = [&](int buf, int kt) {
    const int kbase = kt << 6;
#pragma unroll
    for (int ps = 0; ps < 2; ++ps) {
      int i = ps * 256 + t;
      int r = i >> 3, c = i & 7, cs = c ^ (r & 7);
      async_lds16(sKb + buf * 8192 + i * 16, Kh + (long)(kbase + r) * 64 + cs * 8);
    }
#pragma unroll
    for (int ps = 0; ps < 2; ++ps) {
      int i = ps * 256 + t;
      int d = i >> 3, c = i & 7, cs = c ^ (d & 7);
      async_lds16(sVb + buf * 8192 + i * 16, Vh + (long)d * 2048 + kbase + cs * 8);
    }
  };

  stage(0, 0);
  int cur = 0;
  for (int kt = 0; kt < nkt; ++kt) {
    __syncthreads();  // tile kt staged (vmcnt drain) + everyone done reading buf cur^1
    if (kt + 1 < nkt) stage(cur ^ 1, kt + 1);
    const char* Kt = sKb + cur * 8192;
    const char* Vt = sVb + cur * 8192;
    const int c2 = 2 * kt;
    if (c2 <= strip) {
      if (c2 == strip) attn_sub<true>(Kt, Vt, 0, qf0, qf1, qf2, qf3, acc0, acc1, l, q5, hi);
      else             attn_sub<false>(Kt, Vt, 0, qf0, qf1, qf2, qf3, acc0, acc1, l, q5, hi);
    }
    if (c2 + 1 <= strip) {
      if (c2 + 1 == strip) attn_sub<true>(Kt, Vt, 1, qf0, qf1, qf2, qf3, acc0, acc1, l, q5, hi);
      else                 attn_sub<false>(Kt, Vt, 1, qf0, qf1, qf2, qf3, acc0, acc1, l, q5, hi);
    }
    cur ^= 1;
  }

  // epilogue (no LDS use -> no final barrier)
  l += __shfl_xor(l, 32);
  float linv = 1.0f / l;
  const long orow_base = (long)b * 2048;
#pragma unroll
  for (int r = 0; r < 16; ++r) {
    int crow = (r & 3) + 8 * (r >> 2) + 4 * hi;
    float lf = __shfl(linv, crow);
    long orow = orow_base + q0w + crow;
    Og[orow * 1024 + h * 64 + q5] = f2bf(acc0[r] * lf);
    Og[orow * 1024 + h * 64 + 32 + q5] = f2bf(acc1[r] * lf);
  }
}

// ---------------- launch ----------------

extern "C" void kernel_launch(void* const* d_in, const int* in_sizes, int n_in,
                              void* d_out, int out_size, void* d_ws, size_t ws_size,
                              hipStream_t stream) {
  const float* x = (const float*)d_in[0];
  const float* w_qkv = (const float*)d_in[1];
  const float* w_out = (const float*)d_in[2];
  float* out = (float*)d_out;
  char* ws = (char*)d_ws;

  u16* xb    = (u16*)(ws + 0);          // 8 MB, reused as Ob after attention
  u16* wqkvT = (u16*)(ws + 8388608L);   // 6 MB
  u16* woutT = (u16*)(ws + 14680064L);  // 2 MB
  u16* Qb    = (u16*)(ws + 16777216L);  // 8 MB
  u16* Kb    = (u16*)(ws + 25165824L);  // 8 MB
  u16* Vb    = (u16*)(ws + 33554432L);  // 8 MB
  u16* Vt    = (u16*)(ws + 41943040L);  // 8 MB  (total 48 MB)
  u16* Ob    = xb;                      // alias: xb dead after GEMM1

  k_cvt<<<4096, 256, 0, stream>>>(x, xb, 4194304);
  k_transpose_cvt<<<dim3(96, 32), 256, 0, stream>>>(w_qkv, wqkvT, 1024, 3072);
  k_transpose_cvt<<<dim3(32, 32), 256, 0, stream>>>(w_out, woutT, 1024, 1024);
  k_gemm_qkv<<<dim3(192), 512, 0, stream>>>(xb, wqkvT, Qb, Kb, Vb);
  k_transpose_v<<<dim3(64, 2, 32), 256, 0, stream>>>(Vb, Vt);
  k_attn<<<dim3(512), 256, 0, stream>>>(Qb, Kb, Vt, Ob);
  k_gemm_out<<<dim3(256), 256, 0, stream>>>(Ob, woutT, out);
}

// Round 15
// 122.458 us; speedup vs baseline: 1.1482x; 1.0181x over previous
//
#include <hip/hip_runtime.h>

typedef unsigned short u16;
typedef unsigned int u32;
typedef __attribute__((ext_vector_type(8))) short bf16x8;
typedef __attribute__((ext_vector_type(4))) float f32x4;
typedef __attribute__((ext_vector_type(16))) float f32x16;
typedef __attribute__((ext_vector_type(4))) u32 u32x4;

#define MFMA16(a, b, c) __builtin_amdgcn_mfma_f32_16x16x32_bf16((a), (b), (c), 0, 0, 0)
#define MFMA32(a, b, c) __builtin_amdgcn_mfma_f32_32x32x16_bf16((a), (b), (c), 0, 0, 0)

__device__ __forceinline__ void async_lds16(void* lds, const void* g) {
  __builtin_amdgcn_global_load_lds(
      (const __attribute__((address_space(1))) void*)g,
      (__attribute__((address_space(3))) void*)lds, 16, 0, 0);
}

__device__ __forceinline__ u16 f2bf(float f) {
  union { float f; unsigned u; } v; v.f = f;
  unsigned r = v.u + 0x7fffu + ((v.u >> 16) & 1u);
  return (u16)(r >> 16);
}

__device__ __forceinline__ u32 cvt_pk_bf16(float lo, float hi) {
  u32 r;
  asm("v_cvt_pk_bf16_f32 %0, %1, %2" : "=v"(r) : "v"(lo), "v"(hi));
  return r;
}

__device__ __forceinline__ float exp2_fast(float x) {
  float r;
  asm("v_exp_f32 %0, %1" : "=v"(r) : "v"(x));
  return r;
}

// swaps a's hi-32 lanes with b's lo-32 lanes
__device__ __forceinline__ void pswap(u32& a, u32& b) {
  asm("v_permlane32_swap_b32 %0, %1" : "+v"(a), "+v"(b));
}

// ---------------- preprocess kernels ----------------

__global__ __launch_bounds__(256) void k_cvt(const float* __restrict__ in, u16* __restrict__ out, int n) {
  int i = (blockIdx.x * 256 + threadIdx.x) * 4;
  if (i >= n) return;
  float4 v = *(const float4*)(in + i);
  ushort4 o;
  o.x = f2bf(v.x); o.y = f2bf(v.y); o.z = f2bf(v.z); o.w = f2bf(v.w);
  *(ushort4*)(out + i) = o;
}

// in: f32 [R][C]  ->  out: bf16 [C][R]
__global__ __launch_bounds__(256) void k_transpose_cvt(const float* __restrict__ in, u16* __restrict__ out,
                                                       int R, int C) {
  __shared__ float tile[32][33];
  int c0 = blockIdx.x * 32, r0 = blockIdx.y * 32;
  int tx = threadIdx.x & 31, ty = threadIdx.x >> 5;
#pragma unroll
  for (int i = 0; i < 32; i += 8)
    tile[ty + i][tx] = in[(long)(r0 + ty + i) * C + c0 + tx];
  __syncthreads();
#pragma unroll
  for (int i = 0; i < 32; i += 8)
    out[(long)(c0 + ty + i) * R + r0 + tx] = f2bf(tile[tx][ty + i]);
}

// V [32 bh][2048 s][64 d] -> Vt [32 bh][64 d][2048 s]   (bf16)
__global__ __launch_bounds__(256) void k_transpose_v(const u16* __restrict__ V, u16* __restrict__ Vt) {
  int bh = blockIdx.z;
  int s0 = blockIdx.x * 32, d0 = blockIdx.y * 32;
  __shared__ u16 tile[32][33];
  int tx = threadIdx.x & 31, ty = threadIdx.x >> 5;
  const u16* Vb = V + (long)bh * 2048 * 64;
  u16* Vtb = Vt + (long)bh * 64 * 2048;
#pragma unroll
  for (int i = 0; i < 32; i += 8)
    tile[ty + i][tx] = Vb[(long)(s0 + ty + i) * 64 + d0 + tx];
  __syncthreads();
#pragma unroll
  for (int i = 0; i < 32; i += 8)
    Vtb[(long)(d0 + ty + i) * 2048 + s0 + tx] = tile[tx][ty + i];
}

// ---------------- NT GEMM core (counted-vmcnt single-barrier pipeline) ----------------

template <int BM, int BN, int NW, int WN, int MR, int NR>
__device__ __forceinline__ void gemm_core_pipe(const u16* __restrict__ A, const u16* __restrict__ Bt,
                                               int K, long row0, long col0,
                                               u16* sA, u16* sB, f32x4 (&acc)[MR][NR]) {
  const int NTHR = NW * 64;
  const int ABYTES = BM * 64 * 2;
  const int BBYTES = BN * 64 * 2;
  const int t = threadIdx.x;
  const int lane = t & 63, g = lane >> 4, m16 = lane & 15;
  const int wid = t >> 6, wr = wid / WN, wc = wid % WN;
  const int nkt = K >> 6;

  auto stage = [&](int buf, int kt) {
    const int k0 = kt << 6;
#pragma unroll
    for (int it = 0; it < ABYTES / (NTHR * 16); ++it) {
      int i = it * NTHR + t;
      int r = i >> 3, c = i & 7, cs = c ^ (r & 7);
      async_lds16((char*)sA + buf * ABYTES + i * 16, A + (row0 + r) * K + k0 + cs * 8);
    }
#pragma unroll
    for (int it = 0; it < BBYTES / (NTHR * 16); ++it) {
      int i = it * NTHR + t;
      int r = i >> 3, c = i & 7, cs = c ^ (r & 7);
      async_lds16((char*)sB + buf * BBYTES + i * 16, Bt + (col0 + r) * K + k0 + cs * 8);
    }
  };

  stage(0, 0);
  stage(1, 1);
  int cur = 0;
  for (int kt = 0; kt < nkt; ++kt) {
    if (kt + 1 < nkt) asm volatile("s_waitcnt vmcnt(8)" ::: "memory");
    else              asm volatile("s_waitcnt vmcnt(0)" ::: "memory");
    __builtin_amdgcn_s_barrier();
    __builtin_amdgcn_sched_barrier(0);
    const char* bA = (const char*)sA + cur * ABYTES;
    const char* bB = (const char*)sB + cur * BBYTES;
#pragma unroll
    for (int kk6 = 0; kk6 < 2; ++kk6) {
      const int ke = kk6 * 32 + 8 * g;
      bf16x8 av[MR], bv[NR];
#pragma unroll
      for (int mi = 0; mi < MR; ++mi) {
        int row = wr * (MR * 16) + mi * 16 + m16;
        av[mi] = *(const bf16x8*)(bA + (row << 7) + ((ke << 1) ^ ((row & 7) << 4)));
      }
#pragma unroll
      for (int ni = 0; ni < NR; ++ni) {
        int row = wc * (NR * 16) + ni * 16 + m16;
        bv[ni] = *(const bf16x8*)(bB + (row << 7) + ((ke << 1) ^ ((row & 7) << 4)));
      }
#pragma unroll
      for (int mi = 0; mi < MR; ++mi)
#pragma unroll
        for (int ni = 0; ni < NR; ++ni)
          acc[mi][ni] = MFMA16(av[mi], bv[ni], acc[mi][ni]);
    }
    __builtin_amdgcn_sched_barrier(0);
    __builtin_amdgcn_s_barrier();
    if (kt + 2 < nkt) stage(cur, kt + 2);
    cur ^= 1;
  }
}

// GEMM1: xb[4096][1024] x wqkvT[3072][1024]^T, 256x256 tile, 512 thr (8 waves 2x4).
__global__ __launch_bounds__(512, 2) void k_gemm_qkv(const u16* __restrict__ xb, const u16* __restrict__ wT,
                                                     u16* __restrict__ Qo, u16* __restrict__ Ko,
                                                     u16* __restrict__ Vo) {
  __shared__ __align__(16) u16 sA[2 * 256 * 64];  // 64KB
  __shared__ __align__(16) u16 sB[2 * 256 * 64];  // 64KB
  f32x4 acc[8][4];
  const f32x4 z = {0.f, 0.f, 0.f, 0.f};
#pragma unroll
  for (int mi = 0; mi < 8; ++mi)
#pragma unroll
    for (int ni = 0; ni < 4; ++ni) acc[mi][ni] = z;
  const int L = blockIdx.x;
  const int xcd = L & 7, idx = L >> 3;          // idx 0..23
  const int rowt = xcd * 2 + (idx & 1);         // 0..15
  const int colt = idx >> 1;                    // 0..11
  long row0 = (long)rowt * 256, col0 = (long)colt * 256;
  gemm_core_pipe<256, 256, 8, 4, 8, 4>(xb, wT, 1024, row0, col0, sA, sB, acc);
  const int t = threadIdx.x;
  const int lane = t & 63, g = lane >> 4, m16 = lane & 15;
  const int wid = t >> 6, wr = wid >> 2, wc = wid & 3;
#pragma unroll
  for (int mi = 0; mi < 8; ++mi) {
#pragma unroll
    for (int ni = 0; ni < 4; ++ni) {
      int col = (int)col0 + wc * 64 + ni * 16 + m16;
      int h = col / 192, rem = col - h * 192;
      int which = rem >> 6, d = rem & 63;
#pragma unroll
      for (int r = 0; r < 4; ++r) {
        int row = (int)row0 + wr * 128 + mi * 16 + 4 * g + r;
        int b = row >> 11, s = row & 2047;
        long off = (((long)(b * 16 + h)) * 2048 + s) * 64 + d;
        float v = acc[mi][ni][r];
        if (which == 0) Qo[off] = f2bf(v * 0.18033688f);  // 0.125 * log2(e)
        else if (which == 1) Ko[off] = f2bf(v);
        else Vo[off] = f2bf(v);
      }
    }
  }
}

// GEMM2: Ob[4096][1024] x woutT[1024][1024]^T -> out f32 [4096][1024]
__global__ __launch_bounds__(256) void k_gemm_out(const u16* __restrict__ Ob, const u16* __restrict__ wT,
                                                  float* __restrict__ out) {
  __shared__ __align__(16) u16 sA[2 * 128 * 64];  // 32KB
  __shared__ __align__(16) u16 sB[2 * 128 * 64];  // 32KB
  f32x4 acc[4][4];
  const f32x4 z = {0.f, 0.f, 0.f, 0.f};
#pragma unroll
  for (int mi = 0; mi < 4; ++mi)
#pragma unroll
    for (int ni = 0; ni < 4; ++ni) acc[mi][ni] = z;
  const int L = blockIdx.x;
  const int xcd = L & 7, idx = L >> 3;          // idx 0..31
  const int rowt = xcd * 4 + (idx & 3);         // 0..31
  const int colt = idx >> 2;                    // 0..7
  long row0 = (long)rowt * 128, col0 = (long)colt * 128;
  gemm_core_pipe<128, 128, 4, 2, 4, 4>(Ob, wT, 1024, row0, col0, sA, sB, acc);
  const int t = threadIdx.x;
  const int lane = t & 63, g = lane >> 4, m16 = lane & 15;
  const int wid = t >> 6, wr = wid >> 1, wc = wid & 1;
#pragma unroll
  for (int mi = 0; mi < 4; ++mi) {
#pragma unroll
    for (int ni = 0; ni < 4; ++ni) {
#pragma unroll
      for (int r = 0; r < 4; ++r) {
        long row = row0 + wr * 64 + mi * 16 + 4 * g + r;
        long col = col0 + wc * 64 + ni * 16 + m16;
        out[row * 1024 + col] = acc[mi][ni][r];
      }
    }
  }
}

// ---------------- causal flash attention: pair-merged uniform blocks + counted-vmcnt ----------------
// Block (bh, pr) handles BOTH q-tiles of pair (qtA=pr, qtB=15-pr) in one staged pass
// over the union k-range. Wave w owns heavy strip qtB*4+w AND light strip qtA*4+w:
// per-wave compute = 62+2w sub-blocks, IDENTICAL for every block (placement-free
// balance). Counted-vmcnt single-barrier pipeline (r14 GEMM skeleton): 4 loads per
// thread per tile, vmcnt(4) keeps next tile's loads in flight across the barrier.

template <bool DIAG>
__device__ __forceinline__ void attn_sub(const char* Kt, const char* Vt, int bsub,
                                         bf16x8 qf0, bf16x8 qf1, bf16x8 qf2, bf16x8 qf3,
                                         f32x16& acc0, f32x16& acc1, float& l,
                                         int q5, int hi) {
  const int x7 = q5 & 7;
  const int rowK = (bsub * 32 + q5) << 7;
  bf16x8 k0 = *(const bf16x8*)(Kt + rowK + (((0 + hi) ^ x7) << 4));
  bf16x8 k1 = *(const bf16x8*)(Kt + rowK + (((2 + hi) ^ x7) << 4));
  bf16x8 k2 = *(const bf16x8*)(Kt + rowK + (((4 + hi) ^ x7) << 4));
  bf16x8 k3 = *(const bf16x8*)(Kt + rowK + (((6 + hi) ^ x7) << 4));
  const int rowV0 = q5 << 7, rowV1 = (q5 + 32) << 7;
  bf16x8 v00 = *(const bf16x8*)(Vt + rowV0 + (((bsub * 4 + 0 + hi) ^ x7) << 4));
  bf16x8 v01 = *(const bf16x8*)(Vt + rowV1 + (((bsub * 4 + 0 + hi) ^ x7) << 4));
  bf16x8 v10 = *(const bf16x8*)(Vt + rowV0 + (((bsub * 4 + 2 + hi) ^ x7) << 4));
  bf16x8 v11 = *(const bf16x8*)(Vt + rowV1 + (((bsub * 4 + 2 + hi) ^ x7) << 4));

  f32x16 s;
#pragma unroll
  for (int r = 0; r < 16; ++r) s[r] = 0.f;
  s = MFMA32(k0, qf0, s);
  s = MFMA32(k1, qf1, s);
  s = MFMA32(k2, qf2, s);
  s = MFMA32(k3, qf3, s);

  float p[16];
#pragma unroll
  for (int r = 0; r < 16; ++r) {
    float pv = exp2_fast(s[r]);
    if (DIAG) {
      int crow = (r & 3) + 8 * (r >> 2) + 4 * hi;
      pv = (crow <= q5) ? pv : 0.f;
    }
    p[r] = pv;
  }
  l += (((p[0] + p[1]) + (p[2] + p[3])) + ((p[4] + p[5]) + (p[6] + p[7]))) +
       (((p[8] + p[9]) + (p[10] + p[11])) + ((p[12] + p[13]) + (p[14] + p[15])));

  u32 a0 = cvt_pk_bf16(p[0], p[1]), a1 = cvt_pk_bf16(p[2], p[3]);
  u32 b0 = cvt_pk_bf16(p[4], p[5]), b1 = cvt_pk_bf16(p[6], p[7]);
  pswap(a0, b0); pswap(a1, b1);
  u32 c0 = cvt_pk_bf16(p[8], p[9]), c1 = cvt_pk_bf16(p[10], p[11]);
  u32 d0 = cvt_pk_bf16(p[12], p[13]), d1 = cvt_pk_bf16(p[14], p[15]);
  pswap(c0, d0); pswap(c1, d1);
  u32x4 t0; t0[0] = a0; t0[1] = a1; t0[2] = b0; t0[3] = b1;
  u32x4 t1; t1[0] = c0; t1[1] = c1; t1[2] = d0; t1[3] = d1;
  bf16x8 pa0 = __builtin_bit_cast(bf16x8, t0);  // keys +0..15, k-slot order
  bf16x8 pa1 = __builtin_bit_cast(bf16x8, t1);  // keys +16..31

  acc0 = MFMA32(pa0, v00, acc0);
  acc1 = MFMA32(pa0, v01, acc1);
  acc0 = MFMA32(pa1, v10, acc0);
  acc1 = MFMA32(pa1, v11, acc1);
}

// Q,K: [32 bh][2048][64] bf16 (Q pre-scaled by 0.125*log2e); Vt: [32 bh][64][2048] bf16
__global__ __launch_bounds__(256) void k_attn(const u16* __restrict__ Qg, const u16* __restrict__ Kg,
                                              const u16* __restrict__ Vtg, u16* __restrict__ Og) {
  __shared__ __align__(16) u16 sK[2][64 * 64];  // [key][d] swizzled, 8KB per buffer
  __shared__ __align__(16) u16 sV[2][64 * 64];  // [d][key] swizzled
  const int t = threadIdx.x;
  const int lane = t & 63, q5 = lane & 31, hi = lane >> 5, w = t >> 6;
  const int L = blockIdx.x;
  const int bh = L & 31, pr = L >> 5;           // XCD affinity: L%8 == bh%8; pr 0..7
  const int qtA = pr, qtB = 15 - pr;
  const int b = bh >> 4, h = bh & 15;
  const u16* Qh = Qg + (long)bh * 131072;
  const u16* Kh = Kg + (long)bh * 131072;
  const u16* Vh = Vtg + (long)bh * 131072;
  char* sKb = (char*)sK;
  char* sVb = (char*)sV;

  const int sL_ = qtA * 4 + w, sH_ = qtB * 4 + w;
  const int q0L = sL_ * 32, q0H = sH_ * 32;
  const int nkt = 2 * qtB + 2;  // union k-range (heavy covers light)

  // Q fragments for both strips
  const u16* QpL = Qh + (long)(q0L + q5) * 64 + hi * 8;
  bf16x8 qfL0 = *(const bf16x8*)(QpL);
  bf16x8 qfL1 = *(const bf16x8*)(QpL + 16);
  bf16x8 qfL2 = *(const bf16x8*)(QpL + 32);
  bf16x8 qfL3 = *(const bf16x8*)(QpL + 48);
  const u16* QpH = Qh + (long)(q0H + q5) * 64 + hi * 8;
  bf16x8 qfH0 = *(const bf16x8*)(QpH);
  bf16x8 qfH1 = *(const bf16x8*)(QpH + 16);
  bf16x8 qfH2 = *(const bf16x8*)(QpH + 32);
  bf16x8 qfH3 = *(const bf16x8*)(QpH + 48);

  f32x16 aL0, aL1, aH0, aH1;
#pragma unroll
  for (int r = 0; r < 16; ++r) { aL0[r] = 0.f; aL1[r] = 0.f; aH0[r] = 0.f; aH1[r] = 0.f; }
  float lL = 0.f, lH = 0.f;

  auto stage = [&](int buf, int kt) {
    const int kbase = kt << 6;
#pragma unroll
    for (int ps = 0; ps < 2; ++ps) {
      int i = ps * 256 + t;
      int r = i >> 3, c = i & 7, cs = c ^ (r & 7);
      async_lds16(sKb + buf * 8192 + i * 16, Kh + (long)(kbase + r) * 64 + cs * 8);
    }
#pragma unroll
    for (int ps = 0; ps < 2; ++ps) {
      int i = ps * 256 + t;
      int d = i >> 3, c = i & 7, cs = c ^ (d & 7);
      async_lds16(sVb + buf * 8192 + i * 16, Vh + (long)d * 2048 + kbase + cs * 8);
    }
  };

  stage(0, 0);
  stage(1, 1);
  int cur = 0;
#pragma unroll 1
  for (int kt = 0; kt < nkt; ++kt) {
    if (kt + 1 < nkt) asm volatile("s_waitcnt vmcnt(4)" ::: "memory");
    else              asm volatile("s_waitcnt vmcnt(0)" ::: "memory");
    __builtin_amdgcn_s_barrier();
    __builtin_amdgcn_sched_barrier(0);
    const char* Kt = sKb + cur * 8192;
    const char* Vt = sVb + cur * 8192;
    const int c2 = 2 * kt;
    // heavy strip
    if (c2 <= sH_) {
      if (c2 == sH_) attn_sub<true>(Kt, Vt, 0, qfH0, qfH1, qfH2, qfH3, aH0, aH1, lH, q5, hi);
      else           attn_sub<false>(Kt, Vt, 0, qfH0, qfH1, qfH2, qfH3, aH0, aH1, lH, q5, hi);
    }
    if (c2 + 1 <= sH_) {
      if (c2 + 1 == sH_) attn_sub<true>(Kt, Vt, 1, qfH0, qfH1, qfH2, qfH3, aH0, aH1, lH, q5, hi);
      else               attn_sub<false>(Kt, Vt, 1, qfH0, qfH1, qfH2, qfH3, aH0, aH1, lH, q5, hi);
    }
    // light strip
    if (c2 <= sL_) {
      if (c2 == sL_) attn_sub<true>(Kt, Vt, 0, qfL0, qfL1, qfL2, qfL3, aL0, aL1, lL, q5, hi);
      else           attn_sub<false>(Kt, Vt, 0, qfL0, qfL1, qfL2, qfL3, aL0, aL1, lL, q5, hi);
    }
    if (c2 + 1 <= sL_) {
      if (c2 + 1 == sL_) attn_sub<true>(Kt, Vt, 1, qfL0, qfL1, qfL2, qfL3, aL0, aL1, lL, q5, hi);
      else               attn_sub<false>(Kt, Vt, 1, qfL0, qfL1, qfL2, qfL3, aL0, aL1, lL, q5, hi);
    }
    __builtin_amdgcn_sched_barrier(0);
    __builtin_amdgcn_s_barrier();
    if (kt + 2 < nkt) stage(cur, kt + 2);
    cur ^= 1;
  }

  // epilogues (no LDS use)
  const long orow_base = (long)b * 2048;
  lH += __shfl_xor(lH, 32);
  float liH = 1.0f / lH;
#pragma unroll
  for (int r = 0; r < 16; ++r) {
    int crow = (r & 3) + 8 * (r >> 2) + 4 * hi;
    float lf = __shfl(liH, crow);
    long orow = orow_base + q0H + crow;
    Og[orow * 1024 + h * 64 + q5] = f2bf(aH0[r] * lf);
    Og[orow * 1024 + h * 64 + 32 + q5] = f2bf(aH1[r] * lf);
  }
  lL += __shfl_xor(lL, 32);
  float liL = 1.0f / lL;
#pragma unroll
  for (int r = 0; r < 16; ++r) {
    int crow = (r & 3) + 8 * (r >> 2) + 4 * hi;
    float lf = __shfl(liL, crow);
    long orow = orow_base + q0L + crow;
    Og[orow * 1024 + h * 64 + q5] = f2bf(aL0[r] * lf);
    Og[orow * 1024 + h * 64 + 32 + q5] = f2bf(aL1[r] * lf);
  }
}

// ---------------- launch ----------------

extern "C" void kernel_launch(void* const* d_in, const int* in_sizes, int n_in,
                              void* d_out, int out_size, void* d_ws, size_t ws_size,
                              hipStream_t stream) {
  const float* x = (const float*)d_in[0];
  const float* w_qkv = (const float*)d_in[1];
  const float* w_out = (const float*)d_in[2];
  float* out = (float*)d_out;
  char* ws = (char*)d_ws;

  u16* xb    = (u16*)(ws + 0);          // 8 MB, reused as Ob after attention
  u16* wqkvT = (u16*)(ws + 8388608L);   // 6 MB
  u16* woutT = (u16*)(ws + 14680064L);  // 2 MB
  u16* Qb    = (u16*)(ws + 16777216L);  // 8 MB
  u16* Kb    = (u16*)(ws + 25165824L);  // 8 MB
  u16* Vb    = (u16*)(ws + 33554432L);  // 8 MB
  u16* Vt    = (u16*)(ws + 41943040L);  // 8 MB  (total 48 MB)
  u16* Ob    = xb;                      // alias: xb dead after GEMM1

  k_cvt<<<4096, 256, 0, stream>>>(x, xb, 4194304);
  k_transpose_cvt<<<dim3(96, 32), 256, 0, stream>>>(w_qkv, wqkvT, 1024, 3072);
  k_transpose_cvt<<<dim3(32, 32), 256, 0, stream>>>(w_out, woutT, 1024, 1024);
  k_gemm_qkv<<<dim3(192), 512, 0, stream>>>(xb, wqkvT, Qb, Kb, Vb);
  k_transpose_v<<<dim3(64, 2, 32), 256, 0, stream>>>(Vb, Vt);
  k_attn<<<dim3(256), 256, 0, stream>>>(Qb, Kb, Vt, Ob);
  k_gemm_out<<<dim3(256), 256, 0, stream>>>(Ob, woutT, out);
}

// Round 17
// 113.280 us; speedup vs baseline: 1.2412x; 1.0810x over previous
//
#include <hip/hip_runtime.h>

typedef unsigned short u16;
typedef unsigned int u32;
typedef __attribute__((ext_vector_type(8))) short bf16x8;
typedef __attribute__((ext_vector_type(4))) float f32x4;
typedef __attribute__((ext_vector_type(16))) float f32x16;
typedef __attribute__((ext_vector_type(4))) u32 u32x4;

#define MFMA16(a, b, c) __builtin_amdgcn_mfma_f32_16x16x32_bf16((a), (b), (c), 0, 0, 0)
#define MFMA32(a, b, c) __builtin_amdgcn_mfma_f32_32x32x16_bf16((a), (b), (c), 0, 0, 0)

__device__ __forceinline__ void async_lds16(void* lds, const void* g) {
  __builtin_amdgcn_global_load_lds(
      (const __attribute__((address_space(1))) void*)g,
      (__attribute__((address_space(3))) void*)lds, 16, 0, 0);
}

__device__ __forceinline__ u16 f2bf(float f) {
  union { float f; unsigned u; } v; v.f = f;
  unsigned r = v.u + 0x7fffu + ((v.u >> 16) & 1u);
  return (u16)(r >> 16);
}

__device__ __forceinline__ u32 cvt_pk_bf16(float lo, float hi) {
  u32 r;
  asm("v_cvt_pk_bf16_f32 %0, %1, %2" : "=v"(r) : "v"(lo), "v"(hi));
  return r;
}

__device__ __forceinline__ float exp2_fast(float x) {
  float r;
  asm("v_exp_f32 %0, %1" : "=v"(r) : "v"(x));
  return r;
}

// swaps a's hi-32 lanes with b's lo-32 lanes
__device__ __forceinline__ void pswap(u32& a, u32& b) {
  asm("v_permlane32_swap_b32 %0, %1" : "+v"(a), "+v"(b));
}

// ---------------- fused preprocess kernel ----------------
// blocks [0,4096): f32->bf16 cvt of x; [4096,7168): w_qkv transpose (96x32);
// [7168,8192): w_out transpose (32x32).

__device__ __forceinline__ void transpose_cvt_body(const float* __restrict__ in, u16* __restrict__ out,
                                                   int R, int C, int bx, int by,
                                                   float (*tile)[33]) {
  int c0 = bx * 32, r0 = by * 32;
  int tx = threadIdx.x & 31, ty = threadIdx.x >> 5;
#pragma unroll
  for (int i = 0; i < 32; i += 8)
    tile[ty + i][tx] = in[(long)(r0 + ty + i) * C + c0 + tx];
  __syncthreads();
#pragma unroll
  for (int i = 0; i < 32; i += 8)
    out[(long)(c0 + ty + i) * R + r0 + tx] = f2bf(tile[tx][ty + i]);
}

__global__ __launch_bounds__(256) void k_prep(const float* __restrict__ x, u16* __restrict__ xb,
                                              const float* __restrict__ w_qkv, u16* __restrict__ wqkvT,
                                              const float* __restrict__ w_out, u16* __restrict__ woutT) {
  __shared__ float tile[32][33];
  const int B = blockIdx.x;
  if (B < 4096) {
    int i = (B * 256 + threadIdx.x) * 4;
    float4 v = *(const float4*)(x + i);
    ushort4 o;
    o.x = f2bf(v.x); o.y = f2bf(v.y); o.z = f2bf(v.z); o.w = f2bf(v.w);
    *(ushort4*)(xb + i) = o;
  } else if (B < 7168) {
    int bb = B - 4096;
    transpose_cvt_body(w_qkv, wqkvT, 1024, 3072, bb % 96, bb / 96, tile);
  } else {
    int bb = B - 7168;
    transpose_cvt_body(w_out, woutT, 1024, 1024, bb & 31, bb >> 5, tile);
  }
}

// V [32 bh][2048 s][64 d] -> Vt [32 bh][64 d][2048 s]   (bf16)
__global__ __launch_bounds__(256) void k_transpose_v(const u16* __restrict__ V, u16* __restrict__ Vt) {
  int bh = blockIdx.z;
  int s0 = blockIdx.x * 32, d0 = blockIdx.y * 32;
  __shared__ u16 tile[32][33];
  int tx = threadIdx.x & 31, ty = threadIdx.x >> 5;
  const u16* Vb = V + (long)bh * 2048 * 64;
  u16* Vtb = Vt + (long)bh * 64 * 2048;
#pragma unroll
  for (int i = 0; i < 32; i += 8)
    tile[ty + i][tx] = Vb[(long)(s0 + ty + i) * 64 + d0 + tx];
  __syncthreads();
#pragma unroll
  for (int i = 0; i < 32; i += 8)
    Vtb[(long)(d0 + ty + i) * 2048 + s0 + tx] = tile[tx][ty + i];
}

// ---------------- NT GEMM core (counted-vmcnt single-barrier pipeline) ----------------
// NLD = async loads per thread per K-tile; vmcnt(NLD) keeps exactly the next tile's
// loads in flight across the raw barrier.

template <int BM, int BN, int NW, int WN, int WCS, int MR, int NR, int NLD>
__device__ __forceinline__ void gemm_core_pipe(const u16* __restrict__ A, const u16* __restrict__ Bt,
                                               int K, long row0, long col0,
                                               u16* sA, u16* sB, f32x4 (&acc)[MR][NR]) {
  const int NTHR = NW * 64;
  const int ABYTES = BM * 64 * 2;
  const int BBYTES = BN * 64 * 2;
  const int t = threadIdx.x;
  const int lane = t & 63, g = lane >> 4, m16 = lane & 15;
  const int wid = t >> 6, wr = wid / WN, wc = wid % WN;
  const int nkt = K >> 6;

  auto stage = [&](int buf, int kt) {
    const int k0 = kt << 6;
#pragma unroll
    for (int it = 0; it < ABYTES / (NTHR * 16); ++it) {
      int i = it * NTHR + t;
      int r = i >> 3, c = i & 7, cs = c ^ (r & 7);
      async_lds16((char*)sA + buf * ABYTES + i * 16, A + (row0 + r) * K + k0 + cs * 8);
    }
#pragma unroll
    for (int it = 0; it < BBYTES / (NTHR * 16); ++it) {
      int i = it * NTHR + t;
      int r = i >> 3, c = i & 7, cs = c ^ (r & 7);
      async_lds16((char*)sB + buf * BBYTES + i * 16, Bt + (col0 + r) * K + k0 + cs * 8);
    }
  };

  stage(0, 0);
  stage(1, 1);
  int cur = 0;
  for (int kt = 0; kt < nkt; ++kt) {
    if (kt + 1 < nkt) {
      if constexpr (NLD == 7) asm volatile("s_waitcnt vmcnt(7)" ::: "memory");
      else                    asm volatile("s_waitcnt vmcnt(8)" ::: "memory");
    } else {
      asm volatile("s_waitcnt vmcnt(0)" ::: "memory");
    }
    __builtin_amdgcn_s_barrier();
    __builtin_amdgcn_sched_barrier(0);
    const char* bA = (const char*)sA + cur * ABYTES;
    const char* bB = (const char*)sB + cur * BBYTES;
#pragma unroll
    for (int kk6 = 0; kk6 < 2; ++kk6) {
      const int ke = kk6 * 32 + 8 * g;
      bf16x8 av[MR], bv[NR];
#pragma unroll
      for (int mi = 0; mi < MR; ++mi) {
        int row = wr * (MR * 16) + mi * 16 + m16;
        av[mi] = *(const bf16x8*)(bA + (row << 7) + ((ke << 1) ^ ((row & 7) << 4)));
      }
#pragma unroll
      for (int ni = 0; ni < NR; ++ni) {
        int row = wc * WCS + ni * 16 + m16;
        bv[ni] = *(const bf16x8*)(bB + (row << 7) + ((ke << 1) ^ ((row & 7) << 4)));
      }
#pragma unroll
      for (int mi = 0; mi < MR; ++mi)
#pragma unroll
        for (int ni = 0; ni < NR; ++ni)
          acc[mi][ni] = MFMA16(av[mi], bv[ni], acc[mi][ni]);
    }
    __builtin_amdgcn_sched_barrier(0);
    __builtin_amdgcn_s_barrier();
    if (kt + 2 < nkt) stage(cur, kt + 2);
    cur ^= 1;
  }
}

// GEMM1: xb[4096][1024] x wqkvT[3072][1024]^T, 256x192 tile, 512 thr (8 waves 2x4).
// Grid 256 = 1 block/CU (full chip); col0 = colt*192 -> block maps to head colt.
__global__ __launch_bounds__(512, 2) void k_gemm_qkv(const u16* __restrict__ xb, const u16* __restrict__ wT,
                                                     u16* __restrict__ Qo, u16* __restrict__ Ko,
                                                     u16* __restrict__ Vo) {
  __shared__ __align__(16) u16 sA[2 * 256 * 64];  // 64KB
  __shared__ __align__(16) u16 sB[2 * 192 * 64];  // 48KB
  f32x4 acc[8][3];
  const f32x4 z = {0.f, 0.f, 0.f, 0.f};
#pragma unroll
  for (int mi = 0; mi < 8; ++mi)
#pragma unroll
    for (int ni = 0; ni < 3; ++ni) acc[mi][ni] = z;
  const int L = blockIdx.x;
  const int xcd = L & 7, idx = L >> 3;          // idx 0..31
  const int rowt = xcd * 2 + (idx & 1);         // 0..15
  const int colt = idx >> 1;                    // 0..15 (= head h)
  long row0 = (long)rowt * 256, col0 = (long)colt * 192;
  gemm_core_pipe<256, 192, 8, 4, 48, 8, 3, 7>(xb, wT, 1024, row0, col0, sA, sB, acc);
  const int t = threadIdx.x;
  const int lane = t & 63, g = lane >> 4, m16 = lane & 15;
  const int wid = t >> 6, wr = wid >> 2, wc = wid & 3;
  const int h = colt;
#pragma unroll
  for (int mi = 0; mi < 8; ++mi) {
#pragma unroll
    for (int ni = 0; ni < 3; ++ni) {
      int rem = wc * 48 + ni * 16 + m16;        // 0..191 within head
      int which = rem >> 6, d = rem & 63;
#pragma unroll
      for (int r = 0; r < 4; ++r) {
        int row = (int)row0 + wr * 128 + mi * 16 + 4 * g + r;
        int b = row >> 11, s = row & 2047;
        long off = (((long)(b * 16 + h)) * 2048 + s) * 64 + d;
        float v = acc[mi][ni][r];
        if (which == 0) Qo[off] = f2bf(v * 0.18033688f);  // 0.125 * log2(e)
        else if (which == 1) Ko[off] = f2bf(v);
        else Vo[off] = f2bf(v);
      }
    }
  }
}

// GEMM2: Ob[4096][1024] x woutT[1024][1024]^T -> out f32 [4096][1024]
__global__ __launch_bounds__(256) void k_gemm_out(const u16* __restrict__ Ob, const u16* __restrict__ wT,
                                                  float* __restrict__ out) {
  __shared__ __align__(16) u16 sA[2 * 128 * 64];  // 32KB
  __shared__ __align__(16) u16 sB[2 * 128 * 64];  // 32KB
  f32x4 acc[4][4];
  const f32x4 z = {0.f, 0.f, 0.f, 0.f};
#pragma unroll
  for (int mi = 0; mi < 4; ++mi)
#pragma unroll
    for (int ni = 0; ni < 4; ++ni) acc[mi][ni] = z;
  const int L = blockIdx.x;
  const int xcd = L & 7, idx = L >> 3;          // idx 0..31
  const int rowt = xcd * 4 + (idx & 3);         // 0..31
  const int colt = idx >> 2;                    // 0..7
  long row0 = (long)rowt * 128, col0 = (long)colt * 128;
  gemm_core_pipe<128, 128, 4, 2, 64, 4, 4, 8>(Ob, wT, 1024, row0, col0, sA, sB, acc);
  const int t = threadIdx.x;
  const int lane = t & 63, g = lane >> 4, m16 = lane & 15;
  const int wid = t >> 6, wr = wid >> 1, wc = wid & 1;
#pragma unroll
  for (int mi = 0; mi < 4; ++mi) {
#pragma unroll
    for (int ni = 0; ni < 4; ++ni) {
#pragma unroll
      for (int r = 0; r < 4; ++r) {
        long row = row0 + wr * 64 + mi * 16 + 4 * g + r;
        long col = col0 + wc * 64 + ni * 16 + m16;
        out[row * 1024 + col] = acc[mi][ni][r];
      }
    }
  }
}

// ---------------- causal flash attention: pair-merged uniform blocks + counted-vmcnt ----------------
// (r15 structure, verified; + T5 setprio around MFMA clusters)

template <bool DIAG>
__device__ __forceinline__ void attn_sub(const char* Kt, const char* Vt, int bsub,
                                         bf16x8 qf0, bf16x8 qf1, bf16x8 qf2, bf16x8 qf3,
                                         f32x16& acc0, f32x16& acc1, float& l,
                                         int q5, int hi) {
  const int x7 = q5 & 7;
  const int rowK = (bsub * 32 + q5) << 7;
  bf16x8 k0 = *(const bf16x8*)(Kt + rowK + (((0 + hi) ^ x7) << 4));
  bf16x8 k1 = *(const bf16x8*)(Kt + rowK + (((2 + hi) ^ x7) << 4));
  bf16x8 k2 = *(const bf16x8*)(Kt + rowK + (((4 + hi) ^ x7) << 4));
  bf16x8 k3 = *(const bf16x8*)(Kt + rowK + (((6 + hi) ^ x7) << 4));
  const int rowV0 = q5 << 7, rowV1 = (q5 + 32) << 7;
  bf16x8 v00 = *(const bf16x8*)(Vt + rowV0 + (((bsub * 4 + 0 + hi) ^ x7) << 4));
  bf16x8 v01 = *(const bf16x8*)(Vt + rowV1 + (((bsub * 4 + 0 + hi) ^ x7) << 4));
  bf16x8 v10 = *(const bf16x8*)(Vt + rowV0 + (((bsub * 4 + 2 + hi) ^ x7) << 4));
  bf16x8 v11 = *(const bf16x8*)(Vt + rowV1 + (((bsub * 4 + 2 + hi) ^ x7) << 4));

  f32x16 s;
#pragma unroll
  for (int r = 0; r < 16; ++r) s[r] = 0.f;
  __builtin_amdgcn_s_setprio(1);
  s = MFMA32(k0, qf0, s);
  s = MFMA32(k1, qf1, s);
  s = MFMA32(k2, qf2, s);
  s = MFMA32(k3, qf3, s);
  __builtin_amdgcn_s_setprio(0);

  float p[16];
#pragma unroll
  for (int r = 0; r < 16; ++r) {
    float pv = exp2_fast(s[r]);
    if (DIAG) {
      int crow = (r & 3) + 8 * (r >> 2) + 4 * hi;
      pv = (crow <= q5) ? pv : 0.f;
    }
    p[r] = pv;
  }
  l += (((p[0] + p[1]) + (p[2] + p[3])) + ((p[4] + p[5]) + (p[6] + p[7]))) +
       (((p[8] + p[9]) + (p[10] + p[11])) + ((p[12] + p[13]) + (p[14] + p[15])));

  u32 a0 = cvt_pk_bf16(p[0], p[1]), a1 = cvt_pk_bf16(p[2], p[3]);
  u32 b0 = cvt_pk_bf16(p[4], p[5]), b1 = cvt_pk_bf16(p[6], p[7]);
  pswap(a0, b0); pswap(a1, b1);
  u32 c0 = cvt_pk_bf16(p[8], p[9]), c1 = cvt_pk_bf16(p[10], p[11]);
  u32 d0 = cvt_pk_bf16(p[12], p[13]), d1 = cvt_pk_bf16(p[14], p[15]);
  pswap(c0, d0); pswap(c1, d1);
  u32x4 t0; t0[0] = a0; t0[1] = a1; t0[2] = b0; t0[3] = b1;
  u32x4 t1; t1[0] = c0; t1[1] = c1; t1[2] = d0; t1[3] = d1;
  bf16x8 pa0 = __builtin_bit_cast(bf16x8, t0);  // keys +0..15, k-slot order
  bf16x8 pa1 = __builtin_bit_cast(bf16x8, t1);  // keys +16..31

  __builtin_amdgcn_s_setprio(1);
  acc0 = MFMA32(pa0, v00, acc0);
  acc1 = MFMA32(pa0, v01, acc1);
  acc0 = MFMA32(pa1, v10, acc0);
  acc1 = MFMA32(pa1, v11, acc1);
  __builtin_amdgcn_s_setprio(0);
}

// Q,K: [32 bh][2048][64] bf16 (Q pre-scaled by 0.125*log2e); Vt: [32 bh][64][2048] bf16
__global__ __launch_bounds__(256) void k_attn(const u16* __restrict__ Qg, const u16* __restrict__ Kg,
                                              const u16* __restrict__ Vtg, u16* __restrict__ Og) {
  __shared__ __align__(16) u16 sK[2][64 * 64];  // [key][d] swizzled, 8KB per buffer
  __shared__ __align__(16) u16 sV[2][64 * 64];  // [d][key] swizzled
  const int t = threadIdx.x;
  const int lane = t & 63, q5 = lane & 31, hi = lane >> 5, w = t >> 6;
  const int L = blockIdx.x;
  const int bh = L & 31, pr = L >> 5;           // XCD affinity: L%8 == bh%8; pr 0..7
  const int qtA = pr, qtB = 15 - pr;
  const int b = bh >> 4, h = bh & 15;
  const u16* Qh = Qg + (long)bh * 131072;
  const u16* Kh = Kg + (long)bh * 131072;
  const u16* Vh = Vtg + (long)bh * 131072;
  char* sKb = (char*)sK;
  char* sVb = (char*)sV;

  const int sL_ = qtA * 4 + w, sH_ = qtB * 4 + w;
  const int q0L = sL_ * 32, q0H = sH_ * 32;
  const int nkt = 2 * qtB + 2;  // union k-range (heavy covers light)

  // Q fragments for both strips
  const u16* QpL = Qh + (long)(q0L + q5) * 64 + hi * 8;
  bf16x8 qfL0 = *(const bf16x8*)(QpL);
  bf16x8 qfL1 = *(const bf16x8*)(QpL + 16);
  bf16x8 qfL2 = *(const bf16x8*)(QpL + 32);
  bf16x8 qfL3 = *(const bf16x8*)(QpL + 48);
  const u16* QpH = Qh + (long)(q0H + q5) * 64 + hi * 8;
  bf16x8 qfH0 = *(const bf16x8*)(QpH);
  bf16x8 qfH1 = *(const bf16x8*)(QpH + 16);
  bf16x8 qfH2 = *(const bf16x8*)(QpH + 32);
  bf16x8 qfH3 = *(const bf16x8*)(QpH + 48);

  f32x16 aL0, aL1, aH0, aH1;
#pragma unroll
  for (int r = 0; r < 16; ++r) { aL0[r] = 0.f; aL1[r] = 0.f; aH0[r] = 0.f; aH1[r] = 0.f; }
  float lL = 0.f, lH = 0.f;

  auto stage = [&](int buf, int kt) {
    const int kbase = kt << 6;
#pragma unroll
    for (int ps = 0; ps < 2; ++ps) {
      int i = ps * 256 + t;
      int r = i >> 3, c = i & 7, cs = c ^ (r & 7);
      async_lds16(sKb + buf * 8192 + i * 16, Kh + (long)(kbase + r) * 64 + cs * 8);
    }
#pragma unroll
    for (int ps = 0; ps < 2; ++ps) {
      int i = ps * 256 + t;
      int d = i >> 3, c = i & 7, cs = c ^ (d & 7);
      async_lds16(sVb + buf * 8192 + i * 16, Vh + (long)d * 2048 + kbase + cs * 8);
    }
  };

  stage(0, 0);
  stage(1, 1);
  int cur = 0;
#pragma unroll 1
  for (int kt = 0; kt < nkt; ++kt) {
    if (kt + 1 < nkt) asm volatile("s_waitcnt vmcnt(4)" ::: "memory");
    else              asm volatile("s_waitcnt vmcnt(0)" ::: "memory");
    __builtin_amdgcn_s_barrier();
    __builtin_amdgcn_sched_barrier(0);
    const char* Kt = sKb + cur * 8192;
    const char* Vt = sVb + cur * 8192;
    const int c2 = 2 * kt;
    // heavy strip
    if (c2 <= sH_) {
      if (c2 == sH_) attn_sub<true>(Kt, Vt, 0, qfH0, qfH1, qfH2, qfH3, aH0, aH1, lH, q5, hi);
      else           attn_sub<false>(Kt, Vt, 0, qfH0, qfH1, qfH2, qfH3, aH0, aH1, lH, q5, hi);
    }
    if (c2 + 1 <= sH_) {
      if (c2 + 1 == sH_) attn_sub<true>(Kt, Vt, 1, qfH0, qfH1, qfH2, qfH3, aH0, aH1, lH, q5, hi);
      else               attn_sub<false>(Kt, Vt, 1, qfH0, qfH1, qfH2, qfH3, aH0, aH1, lH, q5, hi);
    }
    // light strip
    if (c2 <= sL_) {
      if (c2 == sL_) attn_sub<true>(Kt, Vt, 0, qfL0, qfL1, qfL2, qfL3, aL0, aL1, lL, q5, hi);
      else           attn_sub<false>(Kt, Vt, 0, qfL0, qfL1, qfL2, qfL3, aL0, aL1, lL, q5, hi);
    }
    if (c2 + 1 <= sL_) {
      if (c2 + 1 == sL_) attn_sub<true>(Kt, Vt, 1, qfL0, qfL1, qfL2, qfL3, aL0, aL1, lL, q5, hi);
      else               attn_sub<false>(Kt, Vt, 1, qfL0, qfL1, qfL2, qfL3, aL0, aL1, lL, q5, hi);
    }
    __builtin_amdgcn_sched_barrier(0);
    __builtin_amdgcn_s_barrier();
    if (kt + 2 < nkt) stage(cur, kt + 2);
    cur ^= 1;
  }

  // epilogues (no LDS use)
  const long orow_base = (long)b * 2048;
  lH += __shfl_xor(lH, 32);
  float liH = 1.0f / lH;
#pragma unroll
  for (int r = 0; r < 16; ++r) {
    int crow = (r & 3) + 8 * (r >> 2) + 4 * hi;
    float lf = __shfl(liH, crow);
    long orow = orow_base + q0H + crow;
    Og[orow * 1024 + h * 64 + q5] = f2bf(aH0[r] * lf);
    Og[orow * 1024 + h * 64 + 32 + q5] = f2bf(aH1[r] * lf);
  }
  lL += __shfl_xor(lL, 32);
  float liL = 1.0f / lL;
#pragma unroll
  for (int r = 0; r < 16; ++r) {
    int crow = (r & 3) + 8 * (r >> 2) + 4 * hi;
    float lf = __shfl(liL, crow);
    long orow = orow_base + q0L + crow;
    Og[orow * 1024 + h * 64 + q5] = f2bf(aL0[r] * lf);
    Og[orow * 1024 + h * 64 + 32 + q5] = f2bf(aL1[r] * lf);
  }
}

// ---------------- launch ----------------

extern "C" void kernel_launch(void* const* d_in, const int* in_sizes, int n_in,
                              void* d_out, int out_size, void* d_ws, size_t ws_size,
                              hipStream_t stream) {
  const float* x = (const float*)d_in[0];
  const float* w_qkv = (const float*)d_in[1];
  const float* w_out = (const float*)d_in[2];
  float* out = (float*)d_out;
  char* ws = (char*)d_ws;

  u16* xb    = (u16*)(ws + 0);          // 8 MB, reused as Ob after attention
  u16* wqkvT = (u16*)(ws + 8388608L);   // 6 MB
  u16* woutT = (u16*)(ws + 14680064L);  // 2 MB
  u16* Qb    = (u16*)(ws + 16777216L);  // 8 MB
  u16* Kb    = (u16*)(ws + 25165824L);  // 8 MB
  u16* Vb    = (u16*)(ws + 33554432L);  // 8 MB
  u16* Vt    = (u16*)(ws + 41943040L);  // 8 MB  (total 48 MB)
  u16* Ob    = xb;                      // alias: xb dead after GEMM1

  k_prep<<<dim3(8192), 256, 0, stream>>>(x, xb, w_qkv, wqkvT, w_out, woutT);
  k_gemm_qkv<<<dim3(256), 512, 0, stream>>>(xb, wqkvT, Qb, Kb, Vb);
  k_transpose_v<<<dim3(64, 2, 32), 256, 0, stream>>>(Vb, Vt);
  k_attn<<<dim3(256), 256, 0, stream>>>(Qb, Kb, Vt, Ob);
  k_gemm_out<<<dim3(256), 256, 0, stream>>>(Ob, woutT, out);
}

// Round 19
// 113.115 us; speedup vs baseline: 1.2431x; 1.0015x over previous
//
#include <hip/hip_runtime.h>

typedef unsigned short u16;
typedef unsigned int u32;
typedef __attribute__((ext_vector_type(8))) short bf16x8;
typedef __attribute__((ext_vector_type(4))) float f32x4;
typedef __attribute__((ext_vector_type(16))) float f32x16;
typedef __attribute__((ext_vector_type(4))) u32 u32x4;

#define MFMA16(a, b, c) __builtin_amdgcn_mfma_f32_16x16x32_bf16((a), (b), (c), 0, 0, 0)
#define MFMA32(a, b, c) __builtin_amdgcn_mfma_f32_32x32x16_bf16((a), (b), (c), 0, 0, 0)

__device__ __forceinline__ void async_lds16(void* lds, const void* g) {
  __builtin_amdgcn_global_load_lds(
      (const __attribute__((address_space(1))) void*)g,
      (__attribute__((address_space(3))) void*)lds, 16, 0, 0);
}

__device__ __forceinline__ u16 f2bf(float f) {
  union { float f; unsigned u; } v; v.f = f;
  unsigned r = v.u + 0x7fffu + ((v.u >> 16) & 1u);
  return (u16)(r >> 16);
}

__device__ __forceinline__ u32 cvt_pk_bf16(float lo, float hi) {
  u32 r;
  asm("v_cvt_pk_bf16_f32 %0, %1, %2" : "=v"(r) : "v"(lo), "v"(hi));
  return r;
}

__device__ __forceinline__ float exp2_fast(float x) {
  float r;
  asm("v_exp_f32 %0, %1" : "=v"(r) : "v"(x));
  return r;
}

// swaps a's hi-32 lanes with b's lo-32 lanes
__device__ __forceinline__ void pswap(u32& a, u32& b) {
  asm("v_permlane32_swap_b32 %0, %1" : "+v"(a), "+v"(b));
}

// ---------------- fused preprocess kernel ----------------
// blocks [0,4096): f32->bf16 cvt of x; [4096,7168): w_qkv transpose (96x32);
// [7168,8192): w_out transpose (32x32).

__device__ __forceinline__ void transpose_cvt_body(const float* __restrict__ in, u16* __restrict__ out,
                                                   int R, int C, int bx, int by,
                                                   float (*tile)[33]) {
  int c0 = bx * 32, r0 = by * 32;
  int tx = threadIdx.x & 31, ty = threadIdx.x >> 5;
#pragma unroll
  for (int i = 0; i < 32; i += 8)
    tile[ty + i][tx] = in[(long)(r0 + ty + i) * C + c0 + tx];
  __syncthreads();
#pragma unroll
  for (int i = 0; i < 32; i += 8)
    out[(long)(c0 + ty + i) * R + r0 + tx] = f2bf(tile[tx][ty + i]);
}

__global__ __launch_bounds__(256) void k_prep(const float* __restrict__ x, u16* __restrict__ xb,
                                              const float* __restrict__ w_qkv, u16* __restrict__ wqkvT,
                                              const float* __restrict__ w_out, u16* __restrict__ woutT) {
  __shared__ float tile[32][33];
  const int B = blockIdx.x;
  if (B < 4096) {
    int i = (B * 256 + threadIdx.x) * 4;
    float4 v = *(const float4*)(x + i);
    ushort4 o;
    o.x = f2bf(v.x); o.y = f2bf(v.y); o.z = f2bf(v.z); o.w = f2bf(v.w);
    *(ushort4*)(xb + i) = o;
  } else if (B < 7168) {
    int bb = B - 4096;
    transpose_cvt_body(w_qkv, wqkvT, 1024, 3072, bb % 96, bb / 96, tile);
  } else {
    int bb = B - 7168;
    transpose_cvt_body(w_out, woutT, 1024, 1024, bb & 31, bb >> 5, tile);
  }
}

// V [32 bh][2048 s][64 d] -> Vt [32 bh][64 d][2048 s]   (bf16)
__global__ __launch_bounds__(256) void k_transpose_v(const u16* __restrict__ V, u16* __restrict__ Vt) {
  int bh = blockIdx.z;
  int s0 = blockIdx.x * 32, d0 = blockIdx.y * 32;
  __shared__ u16 tile[32][33];
  int tx = threadIdx.x & 31, ty = threadIdx.x >> 5;
  const u16* Vb = V + (long)bh * 2048 * 64;
  u16* Vtb = Vt + (long)bh * 64 * 2048;
#pragma unroll
  for (int i = 0; i < 32; i += 8)
    tile[ty + i][tx] = Vb[(long)(s0 + ty + i) * 64 + d0 + tx];
  __syncthreads();
#pragma unroll
  for (int i = 0; i < 32; i += 8)
    Vtb[(long)(d0 + ty + i) * 2048 + s0 + tx] = tile[tx][ty + i];
}

// ---------------- NT GEMM core (counted-vmcnt single-barrier pipeline) ----------------

template <int BM, int BN, int NW, int WN, int WCS, int MR, int NR, int NLD>
__device__ __forceinline__ void gemm_core_pipe(const u16* __restrict__ A, const u16* __restrict__ Bt,
                                               int K, long row0, long col0,
                                               u16* sA, u16* sB, f32x4 (&acc)[MR][NR]) {
  const int NTHR = NW * 64;
  const int ABYTES = BM * 64 * 2;
  const int BBYTES = BN * 64 * 2;
  const int t = threadIdx.x;
  const int lane = t & 63, g = lane >> 4, m16 = lane & 15;
  const int wid = t >> 6, wr = wid / WN, wc = wid % WN;
  const int nkt = K >> 6;

  auto stage = [&](int buf, int kt) {
    const int k0 = kt << 6;
#pragma unroll
    for (int it = 0; it < ABYTES / (NTHR * 16); ++it) {
      int i = it * NTHR + t;
      int r = i >> 3, c = i & 7, cs = c ^ (r & 7);
      async_lds16((char*)sA + buf * ABYTES + i * 16, A + (row0 + r) * K + k0 + cs * 8);
    }
#pragma unroll
    for (int it = 0; it < BBYTES / (NTHR * 16); ++it) {
      int i = it * NTHR + t;
      int r = i >> 3, c = i & 7, cs = c ^ (r & 7);
      async_lds16((char*)sB + buf * BBYTES + i * 16, Bt + (col0 + r) * K + k0 + cs * 8);
    }
  };

  stage(0, 0);
  stage(1, 1);
  int cur = 0;
  for (int kt = 0; kt < nkt; ++kt) {
    if (kt + 1 < nkt) {
      if constexpr (NLD == 7) asm volatile("s_waitcnt vmcnt(7)" ::: "memory");
      else                    asm volatile("s_waitcnt vmcnt(8)" ::: "memory");
    } else {
      asm volatile("s_waitcnt vmcnt(0)" ::: "memory");
    }
    __builtin_amdgcn_s_barrier();
    __builtin_amdgcn_sched_barrier(0);
    const char* bA = (const char*)sA + cur * ABYTES;
    const char* bB = (const char*)sB + cur * BBYTES;
#pragma unroll
    for (int kk6 = 0; kk6 < 2; ++kk6) {
      const int ke = kk6 * 32 + 8 * g;
      bf16x8 av[MR], bv[NR];
#pragma unroll
      for (int mi = 0; mi < MR; ++mi) {
        int row = wr * (MR * 16) + mi * 16 + m16;
        av[mi] = *(const bf16x8*)(bA + (row << 7) + ((ke << 1) ^ ((row & 7) << 4)));
      }
#pragma unroll
      for (int ni = 0; ni < NR; ++ni) {
        int row = wc * WCS + ni * 16 + m16;
        bv[ni] = *(const bf16x8*)(bB + (row << 7) + ((ke << 1) ^ ((row & 7) << 4)));
      }
#pragma unroll
      for (int mi = 0; mi < MR; ++mi)
#pragma unroll
        for (int ni = 0; ni < NR; ++ni)
          acc[mi][ni] = MFMA16(av[mi], bv[ni], acc[mi][ni]);
    }
    __builtin_amdgcn_sched_barrier(0);
    __builtin_amdgcn_s_barrier();
    if (kt + 2 < nkt) stage(cur, kt + 2);
    cur ^= 1;
  }
}

// GEMM1: xb[4096][1024] x wqkvT[3072][1024]^T, 256x192 tile, 512 thr (8 waves 2x4).
// Grid 256 = 1 block/CU; col0 = colt*192 -> block maps to head colt.
__global__ __launch_bounds__(512, 2) void k_gemm_qkv(const u16* __restrict__ xb, const u16* __restrict__ wT,
                                                     u16* __restrict__ Qo, u16* __restrict__ Ko,
                                                     u16* __restrict__ Vo) {
  __shared__ __align__(16) u16 sA[2 * 256 * 64];  // 64KB
  __shared__ __align__(16) u16 sB[2 * 192 * 64];  // 48KB
  f32x4 acc[8][3];
  const f32x4 z = {0.f, 0.f, 0.f, 0.f};
#pragma unroll
  for (int mi = 0; mi < 8; ++mi)
#pragma unroll
    for (int ni = 0; ni < 3; ++ni) acc[mi][ni] = z;
  const int L = blockIdx.x;
  const int xcd = L & 7, idx = L >> 3;          // idx 0..31
  const int rowt = xcd * 2 + (idx & 1);         // 0..15
  const int colt = idx >> 1;                    // 0..15 (= head h)
  long row0 = (long)rowt * 256, col0 = (long)colt * 192;
  gemm_core_pipe<256, 192, 8, 4, 48, 8, 3, 7>(xb, wT, 1024, row0, col0, sA, sB, acc);
  const int t = threadIdx.x;
  const int lane = t & 63, g = lane >> 4, m16 = lane & 15;
  const int wid = t >> 6, wr = wid >> 2, wc = wid & 3;
  const int h = colt;
#pragma unroll
  for (int mi = 0; mi < 8; ++mi) {
#pragma unroll
    for (int ni = 0; ni < 3; ++ni) {
      int rem = wc * 48 + ni * 16 + m16;        // 0..191 within head
      int which = rem >> 6, d = rem & 63;
#pragma unroll
      for (int r = 0; r < 4; ++r) {
        int row = (int)row0 + wr * 128 + mi * 16 + 4 * g + r;
        int b = row >> 11, s = row & 2047;
        long off = (((long)(b * 16 + h)) * 2048 + s) * 64 + d;
        float v = acc[mi][ni][r];
        if (which == 0) Qo[off] = f2bf(v * 0.18033688f);  // 0.125 * log2(e)
        else if (which == 1) Ko[off] = f2bf(v);
        else Vo[off] = f2bf(v);
      }
    }
  }
}

// GEMM2: Ob[4096][1024] x woutT[1024][1024]^T -> out f32 [4096][1024]
__global__ __launch_bounds__(256) void k_gemm_out(const u16* __restrict__ Ob, const u16* __restrict__ wT,
                                                  float* __restrict__ out) {
  __shared__ __align__(16) u16 sA[2 * 128 * 64];  // 32KB
  __shared__ __align__(16) u16 sB[2 * 128 * 64];  // 32KB
  f32x4 acc[4][4];
  const f32x4 z = {0.f, 0.f, 0.f, 0.f};
#pragma unroll
  for (int mi = 0; mi < 4; ++mi)
#pragma unroll
    for (int ni = 0; ni < 4; ++ni) acc[mi][ni] = z;
  const int L = blockIdx.x;
  const int xcd = L & 7, idx = L >> 3;          // idx 0..31
  const int rowt = xcd * 4 + (idx & 3);         // 0..31
  const int colt = idx >> 2;                    // 0..7
  long row0 = (long)rowt * 128, col0 = (long)colt * 128;
  gemm_core_pipe<128, 128, 4, 2, 64, 4, 4, 8>(Ob, wT, 1024, row0, col0, sA, sB, acc);
  const int t = threadIdx.x;
  const int lane = t & 63, g = lane >> 4, m16 = lane & 15;
  const int wid = t >> 6, wr = wid >> 1, wc = wid & 1;
#pragma unroll
  for (int mi = 0; mi < 4; ++mi) {
#pragma unroll
    for (int ni = 0; ni < 4; ++ni) {
#pragma unroll
      for (int r = 0; r < 4; ++r) {
        long row = row0 + wr * 64 + mi * 16 + 4 * g + r;
        long col = col0 + wc * 64 + ni * 16 + m16;
        out[row * 1024 + col] = acc[mi][ni][r];
      }
    }
  }
}

// ---------------- causal flash attention: r17 structure + 4-deep LDS pipeline ----------------
// Block (bh, pr) = 256 thr = 4 waves; wave w owns heavy strip qtB*4+w and light
// strip qtA*4+w (uniform ~64-66 subs/wave). 4 K/V buffers (64KB): tile kt's loads
// are issued 4 tile-times ahead -> L2/L3/HBM latency fully covered; steady-state
// wait is vmcnt(12) (4 loads/thread/tile x 3 tiles in flight), exact 4-case tail.

template <bool DIAG>
__device__ __forceinline__ void attn_sub(const char* Kt, const char* Vt, int bsub,
                                         bf16x8 qf0, bf16x8 qf1, bf16x8 qf2, bf16x8 qf3,
                                         f32x16& acc0, f32x16& acc1, float& l,
                                         int q5, int hi) {
  const int x7 = q5 & 7;
  const int rowK = (bsub * 32 + q5) << 7;
  bf16x8 k0 = *(const bf16x8*)(Kt + rowK + (((0 + hi) ^ x7) << 4));
  bf16x8 k1 = *(const bf16x8*)(Kt + rowK + (((2 + hi) ^ x7) << 4));
  bf16x8 k2 = *(const bf16x8*)(Kt + rowK + (((4 + hi) ^ x7) << 4));
  bf16x8 k3 = *(const bf16x8*)(Kt + rowK + (((6 + hi) ^ x7) << 4));
  const int rowV0 = q5 << 7, rowV1 = (q5 + 32) << 7;
  bf16x8 v00 = *(const bf16x8*)(Vt + rowV0 + (((bsub * 4 + 0 + hi) ^ x7) << 4));
  bf16x8 v01 = *(const bf16x8*)(Vt + rowV1 + (((bsub * 4 + 0 + hi) ^ x7) << 4));
  bf16x8 v10 = *(const bf16x8*)(Vt + rowV0 + (((bsub * 4 + 2 + hi) ^ x7) << 4));
  bf16x8 v11 = *(const bf16x8*)(Vt + rowV1 + (((bsub * 4 + 2 + hi) ^ x7) << 4));

  f32x16 s;
#pragma unroll
  for (int r = 0; r < 16; ++r) s[r] = 0.f;
  __builtin_amdgcn_s_setprio(1);
  s = MFMA32(k0, qf0, s);
  s = MFMA32(k1, qf1, s);
  s = MFMA32(k2, qf2, s);
  s = MFMA32(k3, qf3, s);
  __builtin_amdgcn_s_setprio(0);

  float p[16];
#pragma unroll
  for (int r = 0; r < 16; ++r) {
    float pv = exp2_fast(s[r]);
    if (DIAG) {
      int crow = (r & 3) + 8 * (r >> 2) + 4 * hi;
      pv = (crow <= q5) ? pv : 0.f;
    }
    p[r] = pv;
  }
  l += (((p[0] + p[1]) + (p[2] + p[3])) + ((p[4] + p[5]) + (p[6] + p[7]))) +
       (((p[8] + p[9]) + (p[10] + p[11])) + ((p[12] + p[13]) + (p[14] + p[15])));

  u32 a0 = cvt_pk_bf16(p[0], p[1]), a1 = cvt_pk_bf16(p[2], p[3]);
  u32 b0 = cvt_pk_bf16(p[4], p[5]), b1 = cvt_pk_bf16(p[6], p[7]);
  pswap(a0, b0); pswap(a1, b1);
  u32 c0 = cvt_pk_bf16(p[8], p[9]), c1 = cvt_pk_bf16(p[10], p[11]);
  u32 d0 = cvt_pk_bf16(p[12], p[13]), d1 = cvt_pk_bf16(p[14], p[15]);
  pswap(c0, d0); pswap(c1, d1);
  u32x4 t0; t0[0] = a0; t0[1] = a1; t0[2] = b0; t0[3] = b1;
  u32x4 t1; t1[0] = c0; t1[1] = c1; t1[2] = d0; t1[3] = d1;
  bf16x8 pa0 = __builtin_bit_cast(bf16x8, t0);  // keys +0..15, k-slot order
  bf16x8 pa1 = __builtin_bit_cast(bf16x8, t1);  // keys +16..31

  __builtin_amdgcn_s_setprio(1);
  acc0 = MFMA32(pa0, v00, acc0);
  acc1 = MFMA32(pa0, v01, acc1);
  acc0 = MFMA32(pa1, v10, acc0);
  acc1 = MFMA32(pa1, v11, acc1);
  __builtin_amdgcn_s_setprio(0);
}

// Q,K: [32 bh][2048][64] bf16 (Q pre-scaled by 0.125*log2e); Vt: [32 bh][64][2048] bf16
__global__ __launch_bounds__(256) void k_attn(const u16* __restrict__ Qg, const u16* __restrict__ Kg,
                                              const u16* __restrict__ Vtg, u16* __restrict__ Og) {
  __shared__ __align__(16) u16 sK[4][64 * 64];  // [key][d] swizzled, 8KB per buffer (4-deep)
  __shared__ __align__(16) u16 sV[4][64 * 64];  // [d][key] swizzled
  const int t = threadIdx.x;
  const int lane = t & 63, q5 = lane & 31, hi = lane >> 5, w = t >> 6;
  const int L = blockIdx.x;
  const int bh = L & 31, pr = L >> 5;           // XCD affinity: L%8 == bh%8; pr 0..7
  const int qtA = pr, qtB = 15 - pr;
  const int b = bh >> 4, h = bh & 15;
  const u16* Qh = Qg + (long)bh * 131072;
  const u16* Kh = Kg + (long)bh * 131072;
  const u16* Vh = Vtg + (long)bh * 131072;
  char* sKb = (char*)sK;
  char* sVb = (char*)sV;

  const int sL_ = qtA * 4 + w, sH_ = qtB * 4 + w;
  const int q0L = sL_ * 32, q0H = sH_ * 32;
  const int nkt = 2 * qtB + 2;  // union k-range (>= 18, so 4-tile prologue is safe)

  // Q fragments for both strips
  const u16* QpL = Qh + (long)(q0L + q5) * 64 + hi * 8;
  bf16x8 qfL0 = *(const bf16x8*)(QpL);
  bf16x8 qfL1 = *(const bf16x8*)(QpL + 16);
  bf16x8 qfL2 = *(const bf16x8*)(QpL + 32);
  bf16x8 qfL3 = *(const bf16x8*)(QpL + 48);
  const u16* QpH = Qh + (long)(q0H + q5) * 64 + hi * 8;
  bf16x8 qfH0 = *(const bf16x8*)(QpH);
  bf16x8 qfH1 = *(const bf16x8*)(QpH + 16);
  bf16x8 qfH2 = *(const bf16x8*)(QpH + 32);
  bf16x8 qfH3 = *(const bf16x8*)(QpH + 48);

  f32x16 aL0, aL1, aH0, aH1;
#pragma unroll
  for (int r = 0; r < 16; ++r) { aL0[r] = 0.f; aL1[r] = 0.f; aH0[r] = 0.f; aH1[r] = 0.f; }
  float lL = 0.f, lH = 0.f;

  auto stage = [&](int buf, int kt) {
    const int kbase = kt << 6;
#pragma unroll
    for (int ps = 0; ps < 2; ++ps) {
      int i = ps * 256 + t;
      int r = i >> 3, c = i & 7, cs = c ^ (r & 7);
      async_lds16(sKb + buf * 8192 + i * 16, Kh + (long)(kbase + r) * 64 + cs * 8);
    }
#pragma unroll
    for (int ps = 0; ps < 2; ++ps) {
      int i = ps * 256 + t;
      int d = i >> 3, c = i & 7, cs = c ^ (d & 7);
      async_lds16(sVb + buf * 8192 + i * 16, Vh + (long)d * 2048 + kbase + cs * 8);
    }
  };

  stage(0, 0);
  stage(1, 1);
  stage(2, 2);
  stage(3, 3);
#pragma unroll 1
  for (int kt = 0; kt < nkt; ++kt) {
    const int rem = nkt - kt;
    if (rem > 3)       asm volatile("s_waitcnt vmcnt(12)" ::: "memory");
    else if (rem == 3) asm volatile("s_waitcnt vmcnt(8)" ::: "memory");
    else if (rem == 2) asm volatile("s_waitcnt vmcnt(4)" ::: "memory");
    else               asm volatile("s_waitcnt vmcnt(0)" ::: "memory");
    __builtin_amdgcn_s_barrier();
    __builtin_amdgcn_sched_barrier(0);
    const char* Kt = sKb + (kt & 3) * 8192;
    const char* Vt = sVb + (kt & 3) * 8192;
    const int c2 = 2 * kt;
    // heavy strip
    if (c2 <= sH_) {
      if (c2 == sH_) attn_sub<true>(Kt, Vt, 0, qfH0, qfH1, qfH2, qfH3, aH0, aH1, lH, q5, hi);
      else           attn_sub<false>(Kt, Vt, 0, qfH0, qfH1, qfH2, qfH3, aH0, aH1, lH, q5, hi);
    }
    if (c2 + 1 <= sH_) {
      if (c2 + 1 == sH_) attn_sub<true>(Kt, Vt, 1, qfH0, qfH1, qfH2, qfH3, aH0, aH1, lH, q5, hi);
      else               attn_sub<false>(Kt, Vt, 1, qfH0, qfH1, qfH2, qfH3, aH0, aH1, lH, q5, hi);
    }
    // light strip
    if (c2 <= sL_) {
      if (c2 == sL_) attn_sub<true>(Kt, Vt, 0, qfL0, qfL1, qfL2, qfL3, aL0, aL1, lL, q5, hi);
      else           attn_sub<false>(Kt, Vt, 0, qfL0, qfL1, qfL2, qfL3, aL0, aL1, lL, q5, hi);
    }
    if (c2 + 1 <= sL_) {
      if (c2 + 1 == sL_) attn_sub<true>(Kt, Vt, 1, qfL0, qfL1, qfL2, qfL3, aL0, aL1, lL, q5, hi);
      else               attn_sub<false>(Kt, Vt, 1, qfL0, qfL1, qfL2, qfL3, aL0, aL1, lL, q5, hi);
    }
    __builtin_amdgcn_sched_barrier(0);
    __builtin_amdgcn_s_barrier();
    if (kt + 4 < nkt) stage(kt & 3, kt + 4);
  }

  // epilogues (no LDS use)
  const long orow_base = (long)b * 2048;
  lH += __shfl_xor(lH, 32);
  float liH = 1.0f / lH;
#pragma unroll
  for (int r = 0; r < 16; ++r) {
    int crow = (r & 3) + 8 * (r >> 2) + 4 * hi;
    float lf = __shfl(liH, crow);
    long orow = orow_base + q0H + crow;
    Og[orow * 1024 + h * 64 + q5] = f2bf(aH0[r] * lf);
    Og[orow * 1024 + h * 64 + 32 + q5] = f2bf(aH1[r] * lf);
  }
  lL += __shfl_xor(lL, 32);
  float liL = 1.0f / lL;
#pragma unroll
  for (int r = 0; r < 16; ++r) {
    int crow = (r & 3) + 8 * (r >> 2) + 4 * hi;
    float lf = __shfl(liL, crow);
    long orow = orow_base + q0L + crow;
    Og[orow * 1024 + h * 64 + q5] = f2bf(aL0[r] * lf);
    Og[orow * 1024 + h * 64 + 32 + q5] = f2bf(aL1[r] * lf);
  }
}

// ---------------- launch ----------------

extern "C" void kernel_launch(void* const* d_in, const int* in_sizes, int n_in,
                              void* d_out, int out_size, void* d_ws, size_t ws_size,
                              hipStream_t stream) {
  const float* x = (const float*)d_in[0];
  const float* w_qkv = (const float*)d_in[1];
  const float* w_out = (const float*)d_in[2];
  float* out = (float*)d_out;
  char* ws = (char*)d_ws;

  u16* xb    = (u16*)(ws + 0);          // 8 MB, reused as Ob after attention
  u16* wqkvT = (u16*)(ws + 8388608L);   // 6 MB
  u16* woutT = (u16*)(ws + 14680064L);  // 2 MB
  u16* Qb    = (u16*)(ws + 16777216L);  // 8 MB
  u16* Kb    = (u16*)(ws + 25165824L);  // 8 MB
  u16* Vb    = (u16*)(ws + 33554432L);  // 8 MB
  u16* Vt    = (u16*)(ws + 41943040L);  // 8 MB  (total 48 MB)
  u16* Ob    = xb;                      // alias: xb dead after GEMM1

  k_prep<<<dim3(8192), 256, 0, stream>>>(x, xb, w_qkv, wqkvT, w_out, woutT);
  k_gemm_qkv<<<dim3(256), 512, 0, stream>>>(xb, wqkvT, Qb, Kb, Vb);
  k_transpose_v<<<dim3(64, 2, 32), 256, 0, stream>>>(Vb, Vt);
  k_attn<<<dim3(256), 256, 0, stream>>>(Qb, Kb, Vt, Ob);
  k_gemm_out<<<dim3(256), 256, 0, stream>>>(Ob, woutT, out);
}